// Round 2
// baseline (584.877 us; speedup 1.0000x reference)
//
#include <hip/hip_runtime.h>

// Problem constants (fixed by the reference's setup_inputs)
#define QS_ 512
#define B_  8
#define C_  1024
#define H_  16
#define HC_ 64
#define M_  1536
#define KS_ 512
#define VND 640    // padded new-V row: (L&7)+pad(512)+64+7 <= 583 < 640
#define NITEMS 4096

typedef __attribute__((ext_vector_type(8))) short bf16x8;
typedef __attribute__((ext_vector_type(4))) float f32x4;

__device__ __forceinline__ short f2bf(float f) {
    unsigned u = __float_as_uint(f);
    unsigned r = (u + 0x7FFF + ((u >> 16) & 1)) >> 16;   // RNE
    return (short)r;
}

__device__ __forceinline__ void gload_lds16(const void* g, void* l) {
    __builtin_amdgcn_global_load_lds(
        (const __attribute__((address_space(1))) unsigned int*)g,
        (__attribute__((address_space(3))) unsigned int*)l, 16, 0, 0);
}

// ---------------------------------------------------------------------------
// Fused prep: f32->bf16 convert of xq + 4 weight matrices, memory_kv prep
// (K direct, V transposed), and attention work-counter reset. One launch.
// Blocks [0,4096): converts. Blocks [4096,7168): mkv_prep.
// ---------------------------------------------------------------------------
__global__ __launch_bounds__(256) void prep_all(
    const float* __restrict__ xq,
    const float* __restrict__ w0, const float* __restrict__ w1,
    const float* __restrict__ w2, const float* __restrict__ w3,
    short* __restrict__ xqb,
    short* __restrict__ d0, short* __restrict__ d1,
    short* __restrict__ d2, short* __restrict__ d3,
    const float* __restrict__ mkv, short* __restrict__ kOut,
    short* __restrict__ vOut, int* __restrict__ ctr)
{
    __shared__ short T[64][72];
    const int bx = blockIdx.x;
    if (bx == 0 && threadIdx.x == 0) *ctr = 0;

    if (bx < 4096) {
        // ---- elementwise f32 -> bf16, 8 elems/thread ----
        int idx = bx * 256 + threadIdx.x;         // [0, 1048576)
        const float* src; short* dst; int i;
        if (idx < 524288) { src = xq; dst = xqb; i = idx; }
        else {
            int sel = (idx >> 17) & 3;            // [4..7]&3 -> 0..3
            i = idx & 131071;
            src = sel == 0 ? w0 : sel == 1 ? w1 : sel == 2 ? w2 : w3;
            dst = sel == 0 ? d0 : sel == 1 ? d1 : sel == 2 ? d2 : d3;
        }
        const float4* s = (const float4*)src + (size_t)i * 2;
        float4 a = s[0], bq = s[1];
        short o[8];
        o[0] = f2bf(a.x);  o[1] = f2bf(a.y);  o[2] = f2bf(a.z);  o[3] = f2bf(a.w);
        o[4] = f2bf(bq.x); o[5] = f2bf(bq.y); o[6] = f2bf(bq.z); o[7] = f2bf(bq.w);
        *(uint4*)(dst + (size_t)i * 8) = *(uint4*)o;
        return;
    }

    // ---- mkv_prep: [t][b][h][128] f32 -> K [g][t][64], V [g][hc][1536] ----
    const int idx = bx - 4096;                    // [0, 3072)
    const int tc = idx % 24;
    const int h  = (idx / 24) & 15;
    const int b  = idx / 384;
    const int tid = threadIdx.x;
    const int row = tid >> 2, part = tid & 3;
    const int t = tc * 64 + row;
    const int g = b * H_ + h;
    const float4* src = (const float4*)(mkv + (((size_t)t * B_ + b) * H_ + h) * 128 + part * 32);
    short o[32];
#pragma unroll
    for (int j = 0; j < 8; ++j) {
        float4 f = src[j];
        o[j * 4 + 0] = f2bf(f.x); o[j * 4 + 1] = f2bf(f.y);
        o[j * 4 + 2] = f2bf(f.z); o[j * 4 + 3] = f2bf(f.w);
    }
    if (part < 2) {   // K half: cols 0..63
        short* d = kOut + ((size_t)g * M_ + t) * 64 + part * 32;
#pragma unroll
        for (int j = 0; j < 4; ++j) ((uint4*)d)[j] = ((uint4*)o)[j];
    } else {          // V half: cols 64..127 -> transpose via LDS
        int hc0 = (part - 2) * 32;
#pragma unroll
        for (int j = 0; j < 32; ++j) T[hc0 + j][row] = o[j];
    }
    __syncthreads();
    const int hc = tid >> 2, seg = tid & 3;
    uint4 a = *(const uint4*)&T[hc][seg * 16];
    uint4 c = *(const uint4*)&T[hc][seg * 16 + 8];
    short* d = vOut + ((size_t)g * HC_ + hc) * M_ + tc * 64 + seg * 16;
    ((uint4*)d)[0] = a; ((uint4*)d)[1] = c;
}

// ---------------------------------------------------------------------------
// vbuf [s][b][C] bf16 -> vnewT [b*H+h][hc][VND] at column (L&7)+s
// ---------------------------------------------------------------------------
__global__ __launch_bounds__(256) void v_transpose(
    const short* __restrict__ vbuf, const int* __restrict__ mlen,
    short* __restrict__ vOut)
{
    __shared__ short T[64][72];
    const int sc = blockIdx.x, h = blockIdx.y, b = blockIdx.z;
    const int tid = threadIdx.x;
    const int r = tid >> 2, seg = tid & 3;
    const int s = sc * 64 + r;
    const short* src = vbuf + ((size_t)s * B_ + b) * C_ + h * HC_ + seg * 16;
    short tmp[16];
    *(uint4*)&tmp[0] = ((const uint4*)src)[0];
    *(uint4*)&tmp[8] = ((const uint4*)src)[1];
#pragma unroll
    for (int j = 0; j < 16; ++j) T[seg * 16 + j][r] = tmp[j];
    __syncthreads();
    const int L7 = mlen[b] & 7;
    const int hc = tid >> 2;
    const int g = b * H_ + h;
    short* drow = vOut + ((size_t)g * HC_ + hc) * VND + L7 + sc * 64 + seg * 16;
    const short* srow = &T[hc][seg * 16];
#pragma unroll
    for (int j = 0; j < 16; ++j) drow[j] = srow[j];   // scalar: dst may be odd-aligned
}

// ---------------------------------------------------------------------------
// m97-style bf16 NT GEMM body: 128x128 tile, BK=64, global_load_lds width-16,
// 4 waves each 64x64 quadrant. oscale lets the Q projection fold in the
// attention temperature (0.125 = exact exponent shift in bf16).
// ---------------------------------------------------------------------------
template <bool BF16OUT>
__device__ __forceinline__ void gemm128_body(
    short (*As)[64], short (*Ws)[64],
    const short* __restrict__ A, const short* __restrict__ W,
    const float* __restrict__ bias, void* __restrict__ outv,
    int n0, int j0, float oscale)
{
    const int tid  = threadIdx.x;
    const int lane = tid & 63;
    const int wave = tid >> 6;
    const int wm = (wave & 1) * 64;
    const int wn = (wave >> 1) * 64;
    const int lr = lane & 15;
    const int quad = lane >> 4;

    f32x4 acc[4][4];
#pragma unroll
    for (int i = 0; i < 4; ++i)
#pragma unroll
        for (int j = 0; j < 4; ++j)
            acc[i][j] = (f32x4){0.f, 0.f, 0.f, 0.f};

    for (int k0 = 0; k0 < C_; k0 += 64) {
#pragma unroll
        for (int p = 0; p < 4; ++p) {
            int flat = p * 256 + tid;
            int r = flat >> 3, c8 = (flat & 7) * 8;
            gload_lds16(A + (size_t)(n0 + r) * C_ + k0 + c8, (short*)As + flat * 8);
        }
#pragma unroll
        for (int p = 0; p < 4; ++p) {
            int flat = p * 256 + tid;
            int r = flat >> 3, c8 = (flat & 7) * 8;
            gload_lds16(W + (size_t)(j0 + r) * C_ + k0 + c8, (short*)Ws + flat * 8);
        }
        __syncthreads();
#pragma unroll
        for (int ks = 0; ks < 2; ++ks) {
            const int kk = ks * 32 + quad * 8;
            bf16x8 afrag[4], bfrag[4];
#pragma unroll
            for (int im = 0; im < 4; ++im)
                afrag[im] = *(const bf16x8*)&As[wm + im * 16 + lr][kk];
#pragma unroll
            for (int jn = 0; jn < 4; ++jn)
                bfrag[jn] = *(const bf16x8*)&Ws[wn + jn * 16 + lr][kk];
#pragma unroll
            for (int im = 0; im < 4; ++im)
#pragma unroll
                for (int jn = 0; jn < 4; ++jn)
                    acc[im][jn] = __builtin_amdgcn_mfma_f32_16x16x32_bf16(
                        afrag[im], bfrag[jn], acc[im][jn], 0, 0, 0);
        }
        __syncthreads();
    }

#pragma unroll
    for (int jn = 0; jn < 4; ++jn) {
        const int col = j0 + wn + jn * 16 + lr;
        const float bv = bias[col];
#pragma unroll
        for (int im = 0; im < 4; ++im) {
            const int row = n0 + wm + im * 16 + quad * 4;
#pragma unroll
            for (int r = 0; r < 4; ++r) {
                float v = (acc[im][jn][r] + bv) * oscale;
                if (BF16OUT)
                    ((short*)outv)[(size_t)(row + r) * C_ + col] = f2bf(v);
                else
                    ((float*)outv)[(size_t)(row + r) * C_ + col] = v;
            }
        }
    }
}

template <bool BF16OUT>
__global__ __launch_bounds__(256) void gemm128(
    const short* __restrict__ A, const short* __restrict__ W,
    const float* __restrict__ bias, void* __restrict__ outv)
{
    __shared__ short As[128][64];
    __shared__ short Ws[128][64];
    gemm128_body<BF16OUT>(As, Ws, A, W, bias, outv,
                          blockIdx.x * 128, blockIdx.y * 128, 1.0f);
}

// Fused Q/K/V projection: grid (32, 24). Q output pre-scaled by temperature.
__global__ __launch_bounds__(256) void gemm128_qkv(
    const short* __restrict__ A,
    const short* __restrict__ Wq, const short* __restrict__ Wk,
    const short* __restrict__ Wv,
    const float* __restrict__ bq, const float* __restrict__ bk,
    const float* __restrict__ bv,
    short* __restrict__ oq, short* __restrict__ ok, short* __restrict__ ov)
{
    __shared__ short As[128][64];
    __shared__ short Ws[128][64];
    const int sel = blockIdx.y >> 3;
    const short* W   = sel == 0 ? Wq : sel == 1 ? Wk : Wv;
    const float* bia = sel == 0 ? bq : sel == 1 ? bk : bv;
    short* out       = sel == 0 ? oq : sel == 1 ? ok : ov;
    const float sc   = sel == 0 ? 0.125f : 1.0f;   // temperature folded into Q
    gemm128_body<true>(As, Ws, A, W, bia, out,
                       blockIdx.x * 128, (blockIdx.y & 7) * 128, sc);
}

// ---------------------------------------------------------------------------
// Flash attention, t-split + work-stealing version.
// Item = (g = b*16+h, q-group of 16); 4096 items pulled via global atomic
// counter by 2048 persistent blocks (removes the per-b tend imbalance tail).
// Within a block the 4 waves each take a contiguous quarter of the t-chunks
// with private online-softmax state; partials combined via LDS.
// Per chunk: V loads issued first, next chunk's K prefetched (double-buffer)
// before softmax, so both memory waits hide under softmax/shuffle/PV compute.
// P->bf16 conversion happens BEFORE the cross-quad shuffle (v_cvt_pk +
// v_perm): 8 cvt_pk + 16 shfl + 8 perm vs 32 shfl + 16 f2bf + 16 cndmask.
// ---------------------------------------------------------------------------
__global__ __launch_bounds__(256) void attn_wave(
    const short* __restrict__ qb, const short* __restrict__ kbuf,
    const short* __restrict__ kmem, const short* __restrict__ vmem,
    const short* __restrict__ vnew, const int* __restrict__ mlen,
    const int* __restrict__ padv, const unsigned char* __restrict__ maskb,
    short* __restrict__ xout, int* __restrict__ ctr)
{
    __shared__ float Osh[4][64][17];   // [wave][hc][q], +1 pad
    __shared__ float msh[4][16];
    __shared__ float lsh[4][16];
    __shared__ int item_s;

    const int tid  = threadIdx.x;
    const int lane = tid & 63;
    const int wave = tid >> 6;
    const int lr   = lane & 15;
    const int quad = lane >> 4;
    const float NEG = -1e30f;

    for (;;) {
        if (tid == 0) item_s = atomicAdd(ctr, 1);
        __syncthreads();
        const int item = item_s;
        if (item >= NITEMS) return;

        const int g = item & 127;          // b*16+h
        const int b = g >> 4, h = g & 15;
        const int s0 = (item >> 7) * 16;   // q-group base
        const int L = mlen[b], P = padv[b];
        const int tend = L + P;
        const int Lbase = L & ~7;

        // Q fragments (temperature pre-folded at projection)
        const short* qrow = qb + ((size_t)(s0 + lr) * B_ + b) * C_ + h * HC_;
        bf16x8 q0 = *(const bf16x8*)(qrow + quad * 8);
        bf16x8 q1 = *(const bf16x8*)(qrow + 32 + quad * 8);

        const short* kmb = kmem + (size_t)g * M_ * 64 + quad * 8;
        const short* knb = kbuf + (size_t)b * C_ + h * HC_ + quad * 8;
        const short* vmb = vmem + (size_t)g * HC_ * M_;
        const short* vnb = vnew + (size_t)g * HC_ * VND;
        const int q = s0 + lr;
        const unsigned char* mrow = maskb + (size_t)q * (KS_ * B_) + b;

        f32x4 O[4];
#pragma unroll
        for (int i = 0; i < 4; ++i) O[i] = (f32x4){0.f, 0.f, 0.f, 0.f};
        float mr = NEG, lsum = 0.f;

        const int nch = (tend + 63) >> 6;
        const int cpw = (nch + 3) >> 2;
        const int c0 = wave * cpw;
        const int c1 = min(nch, c0 + cpw);

        bf16x8 kA[4][2], kB[4][2];

        auto loadK = [&](int t0, bf16x8 (&kf)[4][2]) {
#pragma unroll
            for (int tt = 0; tt < 4; ++tt) {
                int t = t0 + tt * 16 + lr;
                const short* p = (t < L)
                    ? (kmb + (size_t)t * 64)
                    : (knb + (size_t)min(t - L, KS_ - 1) * (B_ * C_));
                kf[tt][0] = *(const bf16x8*)p;
                kf[tt][1] = *(const bf16x8*)(p + 32);
            }
        };

        auto chunk = [&](int ci, bf16x8 (&kc)[4][2], bf16x8 (&kn)[4][2]) {
            const int t0 = ci << 6;

            // ---- V fragments issued first: A[m=hc(lr)][k=t] ----
            bf16x8 vf[4][2];
            const bool slowV = (L > t0) && (L < t0 + 64) && ((L & 7) != 0);
            if (!slowV) {
#pragma unroll
                for (int hf = 0; hf < 2; ++hf) {
                    int tf = t0 + hf * 32 + quad * 8;
                    bool inmem = tf < L;
#pragma unroll
                    for (int ht = 0; ht < 4; ++ht) {
                        int hc = ht * 16 + lr;
                        const short* p = inmem ? (vmb + (size_t)hc * M_ + tf)
                                               : (vnb + (size_t)hc * VND + (tf - Lbase));
                        vf[ht][hf] = *(const bf16x8*)p;
                    }
                }
            } else {  // chunk straddles L at non-8-aligned boundary (rare)
#pragma unroll
                for (int hf = 0; hf < 2; ++hf)
#pragma unroll
                    for (int ht = 0; ht < 4; ++ht) {
                        short tmp[8];
                        int hc = ht * 16 + lr;
#pragma unroll
                        for (int j = 0; j < 8; ++j) {
                            int t = t0 + hf * 32 + quad * 8 + j;
                            tmp[j] = (t < L) ? vmb[(size_t)hc * M_ + t]
                                             : vnb[(size_t)hc * VND + (t - Lbase)];
                        }
                        vf[ht][hf] = *(const bf16x8*)tmp;
                    }
            }

            // ---- prefetch next chunk's K (hides under softmax+PV) ----
            if (ci + 1 < c1) loadK((ci + 1) << 6, kn);

            // ---- S^T = K . Q^T (waits on kc, issued a chunk ago) ----
            f32x4 S[4];
#pragma unroll
            for (int tt = 0; tt < 4; ++tt) {
                f32x4 z = (f32x4){0.f, 0.f, 0.f, 0.f};
                z = __builtin_amdgcn_mfma_f32_16x16x32_bf16(kc[tt][0], q0, z, 0, 0, 0);
                S[tt] = __builtin_amdgcn_mfma_f32_16x16x32_bf16(kc[tt][1], q1, z, 0, 0, 0);
            }

            // ---- mask; lane value (tt,r) is (q=lr, t=t0+tt*16+quad*4+r) ----
            float p4[4][4];
#pragma unroll
            for (int tt = 0; tt < 4; ++tt)
#pragma unroll
                for (int r = 0; r < 4; ++r) p4[tt][r] = S[tt][r];
            if (t0 + 63 >= L) {
#pragma unroll
                for (int tt = 0; tt < 4; ++tt) {
                    const int tb = t0 + tt * 16 + quad * 4 - L;
#pragma unroll
                    for (int r = 0; r < 4; ++r) {
                        const int off = tb + r;
                        if (off >= 0) {
                            bool masked = (off >= P) || (mrow[(size_t)off * B_] != 0);
                            if (masked) p4[tt][r] = NEG;
                        }
                    }
                }
            }

            // ---- online softmax (clamped nm: exp(NEG-nm) underflows to 0,
            //      so no per-element NEG cndmask needed) ----
            float rm = NEG;
#pragma unroll
            for (int tt = 0; tt < 4; ++tt)
#pragma unroll
                for (int r = 0; r < 4; ++r) rm = fmaxf(rm, p4[tt][r]);
            rm = fmaxf(rm, __shfl_xor(rm, 16, 64));
            rm = fmaxf(rm, __shfl_xor(rm, 32, 64));
            const float nm = fmaxf(fmaxf(mr, rm), -1e20f);
            const float al = __expf(mr - nm);
            float rs = 0.f;
#pragma unroll
            for (int tt = 0; tt < 4; ++tt)
#pragma unroll
                for (int r = 0; r < 4; ++r) {
                    float e = __expf(p4[tt][r] - nm);
                    p4[tt][r] = e;
                    rs += e;
                }
            rs += __shfl_xor(rs, 16, 64);
            rs += __shfl_xor(rs, 32, 64);
            lsum = lsum * al + rs;
            mr = nm;
#pragma unroll
            for (int ht = 0; ht < 4; ++ht)
#pragma unroll
                for (int r = 0; r < 4; ++r) O[ht][r] *= al;

            // ---- P^T fragments: pack to bf16 BEFORE shuffling.
            //      pk[r] = {hi16=p4[tt0+1][r], lo16=p4[tt0][r]}; one shuffle
            //      moves both; v_perm assembles the bf16x8 words. ----
            bf16x8 pf[2];
            const int slA = ((quad & 1) * 2) * 16 + lr;
            const int slB = slA + 16;
            const unsigned sel = (quad & 2) ? 0x07060302u : 0x05040100u;
#pragma unroll
            for (int hf = 0; hf < 2; ++hf) {
                const int tt0 = hf * 2;
                unsigned pk[4];
#pragma unroll
                for (int r = 0; r < 4; ++r) {
                    unsigned o;
                    asm("v_cvt_pk_bf16_f32 %0, %1, %2"
                        : "=v"(o) : "v"(p4[tt0][r]), "v"(p4[tt0 + 1][r]));
                    pk[r] = o;
                }
                unsigned uA[4], uB[4];
#pragma unroll
                for (int r = 0; r < 4; ++r) {
                    uA[r] = (unsigned)__shfl((int)pk[r], slA, 64);
                    uB[r] = (unsigned)__shfl((int)pk[r], slB, 64);
                }
                unsigned wv[4];
                wv[0] = __builtin_amdgcn_perm(uA[1], uA[0], sel);
                wv[1] = __builtin_amdgcn_perm(uA[3], uA[2], sel);
                wv[2] = __builtin_amdgcn_perm(uB[1], uB[0], sel);
                wv[3] = __builtin_amdgcn_perm(uB[3], uB[2], sel);
                pf[hf] = *(const bf16x8*)wv;
            }

            // ---- O^T += V^T . P^T ----
#pragma unroll
            for (int ht = 0; ht < 4; ++ht) {
                O[ht] = __builtin_amdgcn_mfma_f32_16x16x32_bf16(vf[ht][0], pf[0], O[ht], 0, 0, 0);
                O[ht] = __builtin_amdgcn_mfma_f32_16x16x32_bf16(vf[ht][1], pf[1], O[ht], 0, 0, 0);
            }
        };

        if (c0 < c1) {
            loadK(c0 << 6, kA);
            int ci = c0;
            for (;;) {
                chunk(ci, kA, kB);
                if (++ci >= c1) break;
                chunk(ci, kB, kA);
                if (++ci >= c1) break;
            }
        }

        // ---- write per-wave partials (unnormalized O, m, l) ----
#pragma unroll
        for (int ht = 0; ht < 4; ++ht)
#pragma unroll
            for (int r = 0; r < 4; ++r)
                Osh[wave][ht * 16 + quad * 4 + r][lr] = O[ht][r];
        if (quad == 0) { msh[wave][lr] = mr; lsh[wave][lr] = lsum; }
        __syncthreads();

        // ---- combine 4 partials: thread -> (q = tid>>4, hc = (tid&15)*4) ----
        const int qq  = tid >> 4;
        const int hc0 = (tid & 15) * 4;
        float m0 = msh[0][qq], m1 = msh[1][qq], m2 = msh[2][qq], m3 = msh[3][qq];
        float M = fmaxf(fmaxf(m0, m1), fmaxf(m2, m3));
        float s0f = __expf(m0 - M), s1f = __expf(m1 - M);
        float s2f = __expf(m2 - M), s3f = __expf(m3 - M);
        float l = lsh[0][qq] * s0f + lsh[1][qq] * s1f
                + lsh[2][qq] * s2f + lsh[3][qq] * s3f;
        float inv = (l > 0.f) ? 1.0f / l : 0.f;
        short ov[4];
#pragma unroll
        for (int j = 0; j < 4; ++j) {
            float val = Osh[0][hc0 + j][qq] * s0f + Osh[1][hc0 + j][qq] * s1f
                      + Osh[2][hc0 + j][qq] * s2f + Osh[3][hc0 + j][qq] * s3f;
            ov[j] = f2bf(val * inv);
        }
        short* d = xout + ((size_t)(s0 + qq) * B_ + b) * C_ + h * HC_ + hc0;
        *(long long*)d = *(const long long*)ov;

        __syncthreads();   // protect Osh/item_s reuse across items
    }
}

// ---------------------------------------------------------------------------
extern "C" void kernel_launch(void* const* d_in, const int* in_sizes, int n_in,
                              void* d_out, int out_size, void* d_ws, size_t ws_size,
                              hipStream_t stream)
{
    const float* xq   = (const float*)d_in[0];
    const int*   pad  = (const int*)d_in[1];
    const unsigned char* maskb = (const unsigned char*)d_in[2];
    const int*   mlen = (const int*)d_in[3];
    const float* mkv  = (const float*)d_in[4];
    const float* Wq   = (const float*)d_in[5];
    const float* bq   = (const float*)d_in[6];
    const float* Wk   = (const float*)d_in[7];
    const float* bk   = (const float*)d_in[8];
    const float* Wv   = (const float*)d_in[9];
    const float* bv   = (const float*)d_in[10];
    const float* Wo   = (const float*)d_in[11];
    const float* bo   = (const float*)d_in[12];
    float* out = (float*)d_out;

    // Workspace layout (shorts), ~113 MiB + counter
    short* xqb  = (short*)d_ws;
    short* wqb  = xqb  + (size_t)4194304;                 // 512*8*1024
    short* wkb  = wqb  + (size_t)1048576;
    short* wvb  = wkb  + (size_t)1048576;
    short* wob  = wvb  + (size_t)1048576;
    short* kmem = wob  + (size_t)1048576;                 // 128*1536*64
    short* vmem = kmem + (size_t)128 * M_ * 64;           // 128*64*1536
    short* vnew = vmem + (size_t)128 * HC_ * M_;          // 128*64*640
    short* qbuf = vnew + (size_t)128 * HC_ * VND;
    short* kbuf = qbuf + (size_t)4194304;
    short* vbuf = kbuf + (size_t)4194304;
    short* xbuf = vbuf + (size_t)4194304;
    int*   ctr  = (int*)(xbuf + (size_t)4194304);

    dim3 gblk(256);
    // 1) fused conversions + memory_kv prep + counter reset (one launch)
    prep_all<<<dim3(7168), gblk, 0, stream>>>(
        xq, Wq, Wk, Wv, Wo, xqb, wqb, wkb, wvb, wob, mkv, kmem, vmem, ctr);

    // 2) fused q/k/v projection (bf16 out, Q pre-scaled by temperature)
    gemm128_qkv<<<dim3(32, 24), gblk, 0, stream>>>(
        xqb, wqb, wkb, wvb, bq, bk, bv, qbuf, kbuf, vbuf);
    v_transpose<<<dim3(8, 16, 8), gblk, 0, stream>>>(vbuf, mlen, vnew);

    // 3) work-stealing t-split flash attention
    attn_wave<<<dim3(2048), gblk, 0, stream>>>(qbuf, kbuf, kmem, vmem, vnew,
                                               mlen, pad, maskb, xbuf, ctr);

    // 4) output projection (f32 out)
    gemm128<false><<<dim3(32, 8), gblk, 0, stream>>>(xbuf, wob, bo, out);
}

// Round 4
// 364.324 us; speedup vs baseline: 1.6054x; 1.6054x over previous
//
#include <hip/hip_runtime.h>

// Problem constants (fixed by the reference's setup_inputs)
#define QS_ 512
#define B_  8
#define C_  1024
#define H_  16
#define HC_ 64
#define M_  1536
#define KS_ 512
#define TMX 2048   // merged K/V t-range: ceil((1535+511)/64)*64 = 2048

typedef __attribute__((ext_vector_type(8))) short bf16x8;
typedef __attribute__((ext_vector_type(4))) float f32x4;

__device__ __forceinline__ short f2bf(float f) {
    unsigned u = __float_as_uint(f);
    unsigned r = (u + 0x7FFF + ((u >> 16) & 1)) >> 16;   // RNE
    return (short)r;
}

__device__ __forceinline__ void gload_lds16(const void* g, void* l) {
    __builtin_amdgcn_global_load_lds(
        (const __attribute__((address_space(1))) unsigned int*)g,
        (__attribute__((address_space(3))) unsigned int*)l, 16, 0, 0);
}

// ---------------------------------------------------------------------------
// Fused prep, one launch, block ranges:
//  [0,4096)      : f32->bf16 converts (xq + 4 weights)
//  [4096,7168)   : memory_kv -> kall rows [0,1536) / vall cols [0,1536)
//  [7168,9216)   : zero kall rows [1536,2048)
//  [9216,11264)  : zero vall cols [1536,2048)
//  [11264,11776) : build maskBits[b][q][2048 bits over absolute t] (256B/row)
// ---------------------------------------------------------------------------
__global__ __launch_bounds__(256) void prep_all(
    const float* __restrict__ xq,
    const float* __restrict__ w0, const float* __restrict__ w1,
    const float* __restrict__ w2, const float* __restrict__ w3,
    short* __restrict__ xqb,
    short* __restrict__ d0, short* __restrict__ d1,
    short* __restrict__ d2, short* __restrict__ d3,
    const float* __restrict__ mkv, short* __restrict__ kall,
    short* __restrict__ vall,
    const unsigned char* __restrict__ maskb, const int* __restrict__ mlen,
    const int* __restrict__ padv, unsigned char* __restrict__ mbits)
{
    __shared__ short T[64][72];
    const int bx = blockIdx.x;
    const int tid = threadIdx.x;

    if (bx < 4096) {
        // ---- elementwise f32 -> bf16, 8 elems/thread ----
        int idx = bx * 256 + tid;                 // [0, 1048576)
        const float* src; short* dst; int i;
        if (idx < 524288) { src = xq; dst = xqb; i = idx; }
        else {
            int sel = (idx >> 17) & 3;
            i = idx & 131071;
            src = sel == 0 ? w0 : sel == 1 ? w1 : sel == 2 ? w2 : w3;
            dst = sel == 0 ? d0 : sel == 1 ? d1 : sel == 2 ? d2 : d3;
        }
        const float4* s = (const float4*)src + (size_t)i * 2;
        float4 a = s[0], bq = s[1];
        short o[8];
        o[0] = f2bf(a.x);  o[1] = f2bf(a.y);  o[2] = f2bf(a.z);  o[3] = f2bf(a.w);
        o[4] = f2bf(bq.x); o[5] = f2bf(bq.y); o[6] = f2bf(bq.z); o[7] = f2bf(bq.w);
        *(uint4*)(dst + (size_t)i * 8) = *(uint4*)o;
        return;
    }

    if (bx < 7168) {
        // ---- mkv: [t][b][h][128] f32 -> kall[g][t][64] + vall[g][hc][t] ----
        const int idx = bx - 4096;                // [0, 3072)
        const int tc = idx % 24;
        const int h  = (idx / 24) & 15;
        const int b  = idx / 384;
        const int row = tid >> 2, part = tid & 3;
        const int t = tc * 64 + row;
        const int g = b * H_ + h;
        const float4* src = (const float4*)(mkv + (((size_t)t * B_ + b) * H_ + h) * 128 + part * 32);
        short o[32];
#pragma unroll
        for (int j = 0; j < 8; ++j) {
            float4 f = src[j];
            o[j * 4 + 0] = f2bf(f.x); o[j * 4 + 1] = f2bf(f.y);
            o[j * 4 + 2] = f2bf(f.z); o[j * 4 + 3] = f2bf(f.w);
        }
        if (part < 2) {   // K half: cols 0..63
            short* d = kall + ((size_t)g * TMX + t) * 64 + part * 32;
#pragma unroll
            for (int j = 0; j < 4; ++j) ((uint4*)d)[j] = ((uint4*)o)[j];
        } else {          // V half: cols 64..127 -> transpose via LDS
            int hc0 = (part - 2) * 32;
#pragma unroll
            for (int j = 0; j < 32; ++j) T[hc0 + j][row] = o[j];
        }
        __syncthreads();
        const int hc = tid >> 2, seg = tid & 3;
        uint4 a = *(const uint4*)&T[hc][seg * 16];
        uint4 c = *(const uint4*)&T[hc][seg * 16 + 8];
        short* d = vall + ((size_t)g * HC_ + hc) * TMX + tc * 64 + seg * 16;
        ((uint4*)d)[0] = a; ((uint4*)d)[1] = c;
        return;
    }

    if (bx < 9216) {
        // ---- zero kall rows [1536,2048): per g contiguous 512*64 shorts ----
        int Z = (bx - 7168) * 256 + tid;          // 16B pieces, [0, 524288)
        int gq = Z >> 12, rem = Z & 4095;
        short* d = kall + ((size_t)gq * TMX + 1536) * 64 + rem * 8;
        *(uint4*)d = (uint4){0, 0, 0, 0};
        return;
    }

    if (bx < 11264) {
        // ---- zero vall cols [1536,2048) for all 8192 rows ----
        int Z = (bx - 9216) * 256 + tid;          // [0, 524288)
        int row = Z >> 6, rem = Z & 63;
        short* d = vall + (size_t)row * TMX + 1536 + rem * 8;
        *(uint4*)d = (uint4){0, 0, 0, 0};
        return;
    }

    // ---- maskBits: 2048 bits per (b,q) row (256 bytes). bit(t)=1 -> masked.
    //      t<L: 0 ; off>=P: 1 ; else user mask. One u64 word per thread:
    //      4096 rows x 32 words = 512 blocks x 256 threads. ----
    {
        const int j = bx - 11264;                 // [0, 512)
        const int b = j >> 6;
        const int q = (j & 63) * 8 + (tid >> 5);
        const int wordIdx = tid & 31;             // 64 t-values per word
        const int L = mlen[b], P = padv[b];
        const int tb = wordIdx * 64;
        unsigned long long w;
        if (tb + 63 < L) {
            w = 0ull;                              // fully in memory region
        } else if (tb >= L + P) {
            w = ~0ull;                             // fully past valid range
        } else {
            w = 0ull;
            const unsigned char* mq = maskb + (size_t)q * (KS_ * B_) + b;
#pragma unroll 4
            for (int k = 0; k < 64; ++k) {
                int t = tb + k;
                int bit;
                if (t < L) bit = 0;
                else {
                    int off = t - L;
                    bit = (off >= P) ? 1 : (mq[(size_t)off * B_] ? 1 : 0);
                }
                w |= (unsigned long long)bit << k;
            }
        }
        ((unsigned long long*)mbits)[(((size_t)(b * 512 + q)) << 5) + wordIdx] = w;
    }
}

// ---------------------------------------------------------------------------
// m97-style bf16 NT GEMM body: 128x128 tile, BK=64, global_load_lds width-16.
// oscale folds the attention temperature into the Q projection.
// ---------------------------------------------------------------------------
template <bool BF16OUT>
__device__ __forceinline__ void gemm128_body(
    short (*As)[64], short (*Ws)[64],
    const short* __restrict__ A, const short* __restrict__ W,
    const float* __restrict__ bias, void* __restrict__ outv,
    int n0, int j0, float oscale)
{
    const int tid  = threadIdx.x;
    const int lane = tid & 63;
    const int wave = tid >> 6;
    const int wm = (wave & 1) * 64;
    const int wn = (wave >> 1) * 64;
    const int lr = lane & 15;
    const int quad = lane >> 4;

    f32x4 acc[4][4];
#pragma unroll
    for (int i = 0; i < 4; ++i)
#pragma unroll
        for (int j = 0; j < 4; ++j)
            acc[i][j] = (f32x4){0.f, 0.f, 0.f, 0.f};

    for (int k0 = 0; k0 < C_; k0 += 64) {
#pragma unroll
        for (int p = 0; p < 4; ++p) {
            int flat = p * 256 + tid;
            int r = flat >> 3, c8 = (flat & 7) * 8;
            gload_lds16(A + (size_t)(n0 + r) * C_ + k0 + c8, (short*)As + flat * 8);
        }
#pragma unroll
        for (int p = 0; p < 4; ++p) {
            int flat = p * 256 + tid;
            int r = flat >> 3, c8 = (flat & 7) * 8;
            gload_lds16(W + (size_t)(j0 + r) * C_ + k0 + c8, (short*)Ws + flat * 8);
        }
        __syncthreads();
#pragma unroll
        for (int ks = 0; ks < 2; ++ks) {
            const int kk = ks * 32 + quad * 8;
            bf16x8 afrag[4], bfrag[4];
#pragma unroll
            for (int im = 0; im < 4; ++im)
                afrag[im] = *(const bf16x8*)&As[wm + im * 16 + lr][kk];
#pragma unroll
            for (int jn = 0; jn < 4; ++jn)
                bfrag[jn] = *(const bf16x8*)&Ws[wn + jn * 16 + lr][kk];
#pragma unroll
            for (int im = 0; im < 4; ++im)
#pragma unroll
                for (int jn = 0; jn < 4; ++jn)
                    acc[im][jn] = __builtin_amdgcn_mfma_f32_16x16x32_bf16(
                        afrag[im], bfrag[jn], acc[im][jn], 0, 0, 0);
        }
        __syncthreads();
    }

#pragma unroll
    for (int jn = 0; jn < 4; ++jn) {
        const int col = j0 + wn + jn * 16 + lr;
        const float bv = bias[col];
#pragma unroll
        for (int im = 0; im < 4; ++im) {
            const int row = n0 + wm + im * 16 + quad * 4;
#pragma unroll
            for (int r = 0; r < 4; ++r) {
                float v = (acc[im][jn][r] + bv) * oscale;
                if (BF16OUT)
                    ((short*)outv)[(size_t)(row + r) * C_ + col] = f2bf(v);
                else
                    ((float*)outv)[(size_t)(row + r) * C_ + col] = v;
            }
        }
    }
}

template <bool BF16OUT>
__global__ __launch_bounds__(256) void gemm128(
    const short* __restrict__ A, const short* __restrict__ W,
    const float* __restrict__ bias, void* __restrict__ outv)
{
    __shared__ short As[128][64];
    __shared__ short Ws[128][64];
    gemm128_body<BF16OUT>(As, Ws, A, W, bias, outv,
                          blockIdx.x * 128, blockIdx.y * 128, 1.0f);
}

// Fused Q/K/V projection: grid (32, 24). Q output pre-scaled by temperature.
__global__ __launch_bounds__(256) void gemm128_qkv(
    const short* __restrict__ A,
    const short* __restrict__ Wq, const short* __restrict__ Wk,
    const short* __restrict__ Wv,
    const float* __restrict__ bq, const float* __restrict__ bk,
    const float* __restrict__ bv,
    short* __restrict__ oq, short* __restrict__ ok, short* __restrict__ ov)
{
    __shared__ short As[128][64];
    __shared__ short Ws[128][64];
    const int sel = blockIdx.y >> 3;
    const short* W   = sel == 0 ? Wq : sel == 1 ? Wk : Wv;
    const float* bia = sel == 0 ? bq : sel == 1 ? bk : bv;
    short* out       = sel == 0 ? oq : sel == 1 ? ok : ov;
    const float sc   = sel == 0 ? 0.125f : 1.0f;
    gemm128_body<true>(As, Ws, A, W, bia, out,
                       blockIdx.x * 128, (blockIdx.y & 7) * 128, sc);
}

// ---------------------------------------------------------------------------
// Scatter new K/V into the merged absolute-t buffers.
//  [0,1024)    : vbuf [s][b][C] -> vall[g][hc][L+s]   (LDS transpose, scalar st)
//  [1024,3072) : kbuf [s][b][C] -> kall[g][L+s][hc]   (16B aligned copies)
// ---------------------------------------------------------------------------
__global__ __launch_bounds__(256) void scatter_kv(
    const short* __restrict__ vbuf, const short* __restrict__ kbuf,
    const int* __restrict__ mlen, short* __restrict__ vall,
    short* __restrict__ kall)
{
    const int bx = blockIdx.x;
    const int tid = threadIdx.x;
    if (bx < 1024) {
        __shared__ short T[64][72];
        const int sc = bx & 7, h = (bx >> 3) & 15, b = bx >> 7;
        const int r = tid >> 2, seg = tid & 3;
        const int s = sc * 64 + r;
        const short* src = vbuf + ((size_t)s * B_ + b) * C_ + h * HC_ + seg * 16;
        short tmp[16];
        *(uint4*)&tmp[0] = ((const uint4*)src)[0];
        *(uint4*)&tmp[8] = ((const uint4*)src)[1];
#pragma unroll
        for (int j = 0; j < 16; ++j) T[seg * 16 + j][r] = tmp[j];
        __syncthreads();
        const int L = mlen[b];
        const int hc = tid >> 2;
        const int g = b * H_ + h;
        short* drow = vall + ((size_t)g * HC_ + hc) * TMX + L + sc * 64 + seg * 16;
        const short* srow = &T[hc][seg * 16];
#pragma unroll
        for (int j = 0; j < 16; ++j) drow[j] = srow[j];  // dst may be odd-aligned
        return;
    }
    // k_append: 16B pieces
    int Pc = (bx - 1024) * 256 + tid;        // [0, 524288)
    int sb = Pc >> 7;
    int s = sb >> 3, b = sb & 7;
    int c8 = (Pc & 127) * 8;
    int h = c8 >> 6, hc = c8 & 63;
    const uint4* src = (const uint4*)(kbuf + (size_t)sb * C_ + c8);
    int L = mlen[b];
    uint4* dst = (uint4*)(kall + ((size_t)(b * 16 + h) * TMX + L + s) * 64 + hc);
    *dst = *src;
}

// ---------------------------------------------------------------------------
// Flash attention, LDS-staged 2-phase pipeline.
// Block = (g, 64 q-rows); 4 waves x 16 q, barrier-synced over the shared
// t-chunk stream. K/V staged via global_load_lds (no VGPR cost) into
// double-buffered, XOR-swizzled LDS (swizzle applied to the GLOBAL source,
// rule #21). Mask = precomputed absolute-t bit vector: 1 load + ~24 VALU.
// Grid 1024 blocks, 32KB LDS -> 4 blocks/CU -> ALL blocks co-resident.
// b = (bx + bx>>3)&7 gives each CU 4 distinct b (load balance).
// ---------------------------------------------------------------------------
__global__ __launch_bounds__(256, 4) void attn_block(
    const short* __restrict__ qb, const short* __restrict__ kall,
    const short* __restrict__ vall, const unsigned char* __restrict__ mbits,
    const int* __restrict__ mlen, const int* __restrict__ padv,
    short* __restrict__ xout)
{
    __shared__ short Ks[2][64][64];   // [buf][t][hc], 128B rows, swizzled
    __shared__ short Vs[2][64][64];   // [buf][hc][t], 128B rows, swizzled

    const int tid  = threadIdx.x;
    const int lane = tid & 63;
    const int wave = tid >> 6;
    const int lr   = lane & 15;
    const int quad = lane >> 4;
    const int bx = blockIdx.x;
    const int b  = (bx + (bx >> 3)) & 7;
    const int h  = (bx >> 3) & 15;
    const int qg = bx >> 7;
    const int g  = b * 16 + h;
    const int tend = mlen[b] + padv[b];
    const float NEG = -1e30f;

    const int q = qg * 64 + wave * 16 + lr;

    const short* qrow = qb + ((size_t)q * B_ + b) * C_ + h * HC_;
    bf16x8 q0 = *(const bf16x8*)(qrow + quad * 8);
    bf16x8 q1 = *(const bf16x8*)(qrow + 32 + quad * 8);

    const char* kg = (const char*)(kall + (size_t)g * TMX * 64);
    const char* vg = (const char*)(vall + (size_t)g * HC_ * TMX);
    const unsigned char* mrow = mbits + ((size_t)(b * 512 + q) << 8);  // 256B/row

    f32x4 O[4];
#pragma unroll
    for (int i = 0; i < 4; ++i) O[i] = (f32x4){0.f, 0.f, 0.f, 0.f};
    float mr = NEG, lsum = 0.f;

    const int nch = (tend + 63) >> 6;

    // Stage one chunk: waves 0,1 stage K (8KB), waves 2,3 stage V (8KB).
    // Dest is linear; source column pre-swizzled with c ^= ((row&7)<<4).
    auto stage = [&](int t0, int buf) {
        char* KsB = (char*)Ks[buf];
        char* VsB = (char*)Vs[buf];
#pragma unroll
        for (int i = 0; i < 4; ++i) {
            int p = wave * 4 + i;
            int f = ((p & 7) << 6) + lane;        // [0,512) 16B pieces
            int row = f >> 3;
            int c = ((f & 7) << 4) ^ ((row & 7) << 4);
            if (p < 8)
                gload_lds16(kg + (size_t)(t0 + row) * 128 + c,
                            KsB + (size_t)f * 16);
            else
                gload_lds16(vg + (size_t)row * (TMX * 2) + (size_t)t0 * 2 + c,
                            VsB + (size_t)f * 16);
        }
    };

    if (nch > 0) stage(0, 0);
    __syncthreads();

    int cur = 0;
    for (int ci = 0; ci < nch; ++ci) {
        const int t0 = ci << 6;

        // mask bits for this lane's q row, t in [t0, t0+64)
        unsigned long long mw = *(const unsigned long long*)(mrow + (t0 >> 3));

        // stage next chunk into the other buffer (drained by end barrier)
        if (ci + 1 < nch) stage((ci + 1) << 6, cur ^ 1);

        const char* KsB = (const char*)Ks[cur];
        const char* VsB = (const char*)Vs[cur];

        // ---- K fragments: A[m=t(lr)][k=hc(quad*8+j)] ----
        bf16x8 kf[4][2];
#pragma unroll
        for (int tt = 0; tt < 4; ++tt) {
            int t = tt * 16 + lr;
            int sw = (t & 7) << 4;
            kf[tt][0] = *(const bf16x8*)(KsB + t * 128 + ((quad * 16) ^ sw));
            kf[tt][1] = *(const bf16x8*)(KsB + t * 128 + ((64 + quad * 16) ^ sw));
        }

        // ---- S^T = K . Q^T ----
        __builtin_amdgcn_s_setprio(1);
        f32x4 S[4];
#pragma unroll
        for (int tt = 0; tt < 4; ++tt) {
            f32x4 z = (f32x4){0.f, 0.f, 0.f, 0.f};
            z = __builtin_amdgcn_mfma_f32_16x16x32_bf16(kf[tt][0], q0, z, 0, 0, 0);
            S[tt] = __builtin_amdgcn_mfma_f32_16x16x32_bf16(kf[tt][1], q1, z, 0, 0, 0);
        }
        __builtin_amdgcn_s_setprio(0);

        // ---- V fragments (LDS reads issued now, used at PV) ----
        bf16x8 vf[4][2];
#pragma unroll
        for (int ht = 0; ht < 4; ++ht) {
            int hc = ht * 16 + lr;
            int sw = (hc & 7) << 4;
            vf[ht][0] = *(const bf16x8*)(VsB + hc * 128 + ((quad * 16) ^ sw));
            vf[ht][1] = *(const bf16x8*)(VsB + hc * 128 + ((64 + quad * 16) ^ sw));
        }

        // ---- mask; lane value (tt,r) is (q, t=t0+tt*16+quad*4+r) ----
        float p4[4][4];
#pragma unroll
        for (int tt = 0; tt < 4; ++tt) {
            unsigned m4 = ((unsigned)(mw >> (tt * 16 + quad * 4))) & 15u;
#pragma unroll
            for (int r = 0; r < 4; ++r)
                p4[tt][r] = (m4 & (1u << r)) ? NEG : S[tt][r];
        }

        // ---- online softmax (cross-quad reduce via xor 16,32) ----
        float rm = NEG;
#pragma unroll
        for (int tt = 0; tt < 4; ++tt)
#pragma unroll
            for (int r = 0; r < 4; ++r) rm = fmaxf(rm, p4[tt][r]);
        rm = fmaxf(rm, __shfl_xor(rm, 16, 64));
        rm = fmaxf(rm, __shfl_xor(rm, 32, 64));
        const float nm = fmaxf(fmaxf(mr, rm), -1e20f);
        const float al = __expf(mr - nm);
        float rs = 0.f;
#pragma unroll
        for (int tt = 0; tt < 4; ++tt)
#pragma unroll
            for (int r = 0; r < 4; ++r) {
                float e = __expf(p4[tt][r] - nm);
                p4[tt][r] = e;
                rs += e;
            }
        rs += __shfl_xor(rs, 16, 64);
        rs += __shfl_xor(rs, 32, 64);
        lsum = lsum * al + rs;
        mr = nm;
#pragma unroll
        for (int ht = 0; ht < 4; ++ht)
#pragma unroll
            for (int r = 0; r < 4; ++r) O[ht][r] *= al;

        // ---- P^T fragments: pack to bf16 before shuffling ----
        bf16x8 pf[2];
        const int slA = ((quad & 1) * 2) * 16 + lr;
        const int slB = slA + 16;
        const unsigned sel = (quad & 2) ? 0x07060302u : 0x05040100u;
#pragma unroll
        for (int hf = 0; hf < 2; ++hf) {
            const int tt0 = hf * 2;
            unsigned pk[4];
#pragma unroll
            for (int r = 0; r < 4; ++r) {
                unsigned o;
                asm("v_cvt_pk_bf16_f32 %0, %1, %2"
                    : "=v"(o) : "v"(p4[tt0][r]), "v"(p4[tt0 + 1][r]));
                pk[r] = o;
            }
            unsigned uA[4], uB[4];
#pragma unroll
            for (int r = 0; r < 4; ++r) {
                uA[r] = (unsigned)__shfl((int)pk[r], slA, 64);
                uB[r] = (unsigned)__shfl((int)pk[r], slB, 64);
            }
            unsigned wv[4];
            wv[0] = __builtin_amdgcn_perm(uA[1], uA[0], sel);
            wv[1] = __builtin_amdgcn_perm(uA[3], uA[2], sel);
            wv[2] = __builtin_amdgcn_perm(uB[1], uB[0], sel);
            wv[3] = __builtin_amdgcn_perm(uB[3], uB[2], sel);
            pf[hf] = *(const bf16x8*)wv;
        }

        // ---- O^T += V^T . P^T ----
        __builtin_amdgcn_s_setprio(1);
#pragma unroll
        for (int ht = 0; ht < 4; ++ht) {
            O[ht] = __builtin_amdgcn_mfma_f32_16x16x32_bf16(vf[ht][0], pf[0], O[ht], 0, 0, 0);
            O[ht] = __builtin_amdgcn_mfma_f32_16x16x32_bf16(vf[ht][1], pf[1], O[ht], 0, 0, 0);
        }
        __builtin_amdgcn_s_setprio(0);

        __syncthreads();   // drains this iter's stage (vmcnt 0) + buffer reuse
        cur ^= 1;
    }

    // ---- epilogue: O^T row=hc=ht*16+quad*4+r, col=q ----
    float inv = (lsum > 0.f) ? 1.0f / lsum : 0.f;
#pragma unroll
    for (int ht = 0; ht < 4; ++ht) {
        short ov[4];
#pragma unroll
        for (int r = 0; r < 4; ++r) ov[r] = f2bf(O[ht][r] * inv);
        short* d = xout + ((size_t)q * B_ + b) * C_ + h * HC_ + ht * 16 + quad * 4;
        *(long long*)d = *(const long long*)ov;
    }
}

// ---------------------------------------------------------------------------
extern "C" void kernel_launch(void* const* d_in, const int* in_sizes, int n_in,
                              void* d_out, int out_size, void* d_ws, size_t ws_size,
                              hipStream_t stream)
{
    const float* xq   = (const float*)d_in[0];
    const int*   pad  = (const int*)d_in[1];
    const unsigned char* maskb = (const unsigned char*)d_in[2];
    const int*   mlen = (const int*)d_in[3];
    const float* mkv  = (const float*)d_in[4];
    const float* Wq   = (const float*)d_in[5];
    const float* bq   = (const float*)d_in[6];
    const float* Wk   = (const float*)d_in[7];
    const float* bk   = (const float*)d_in[8];
    const float* Wv   = (const float*)d_in[9];
    const float* bv   = (const float*)d_in[10];
    const float* Wo   = (const float*)d_in[11];
    const float* bo   = (const float*)d_in[12];
    float* out = (float*)d_out;

    // Workspace layout (shorts), ~113 MiB + 1 MiB mask bits
    short* xqb  = (short*)d_ws;
    short* wqb  = xqb  + (size_t)4194304;                 // 512*8*1024
    short* wkb  = wqb  + (size_t)1048576;
    short* wvb  = wkb  + (size_t)1048576;
    short* wob  = wvb  + (size_t)1048576;
    short* kall = wob  + (size_t)1048576;                 // 128*2048*64
    short* vall = kall + (size_t)128 * TMX * 64;          // 128*64*2048
    short* qbuf = vall + (size_t)128 * HC_ * TMX;
    short* kbuf = qbuf + (size_t)4194304;
    short* vbuf = kbuf + (size_t)4194304;
    short* xbuf = vbuf + (size_t)4194304;
    unsigned char* mbits = (unsigned char*)(xbuf + (size_t)4194304); // 1MB

    dim3 gblk(256);
    // 1) converts + mkv merge-prep + tail zeroing + mask bit build
    prep_all<<<dim3(11776), gblk, 0, stream>>>(
        xq, Wq, Wk, Wv, Wo, xqb, wqb, wkb, wvb, wob,
        mkv, kall, vall, maskb, mlen, pad, mbits);

    // 2) fused q/k/v projection (bf16 out, Q pre-scaled by temperature)
    gemm128_qkv<<<dim3(32, 24), gblk, 0, stream>>>(
        xqb, wqb, wkb, wvb, bq, bk, bv, qbuf, kbuf, vbuf);

    // 3) scatter new K/V into merged absolute-t buffers
    scatter_kv<<<dim3(3072), gblk, 0, stream>>>(vbuf, kbuf, mlen, vall, kall);

    // 4) LDS-staged flash attention (all 1024 blocks co-resident)
    attn_block<<<dim3(1024), gblk, 0, stream>>>(qbuf, kall, vall, mbits,
                                                mlen, pad, xbuf);

    // 5) output projection (f32 out)
    gemm128<false><<<dim3(32, 8), gblk, 0, stream>>>(xbuf, wob, bo, out);
}

// Round 6
// 345.814 us; speedup vs baseline: 1.6913x; 1.0535x over previous
//
#include <hip/hip_runtime.h>

// Problem constants (fixed by the reference's setup_inputs)
#define QS_ 512
#define B_  8
#define C_  1024
#define H_  16
#define HC_ 64
#define M_  1536
#define KS_ 512
#define TMX 2048   // merged K/V t-range: ceil((1535+511)/64)*64 = 2048

typedef __attribute__((ext_vector_type(8))) short bf16x8;
typedef __attribute__((ext_vector_type(4))) float f32x4;

__device__ __forceinline__ short f2bf(float f) {
    unsigned u = __float_as_uint(f);
    unsigned r = (u + 0x7FFF + ((u >> 16) & 1)) >> 16;   // RNE
    return (short)r;
}

__device__ __forceinline__ void gload_lds16(const void* g, void* l) {
    __builtin_amdgcn_global_load_lds(
        (const __attribute__((address_space(1))) unsigned int*)g,
        (__attribute__((address_space(3))) unsigned int*)l, 16, 0, 0);
}

// ---------------------------------------------------------------------------
// Fused prep, one launch, block ranges:
//  [0,4096)     : f32->bf16 converts (xq + 4 weights)
//  [4096,7168)  : memory_kv -> kall rows [0,1536) / vall cols [0,1536)
//  [7168,7296)  : zero vall tail window [max(1536,L+512), ceil64(L+P)) per (b,h)
//                 (K tail needs NO zeroing: garbage is masked by selection;
//                  V needs finite values where P=0 would multiply NaN garbage)
//  [7296,7808)  : build maskBits[b][q][2048 bits over absolute t] (256B/row)
// ---------------------------------------------------------------------------
__global__ __launch_bounds__(256) void prep_all(
    const float* __restrict__ xq,
    const float* __restrict__ w0, const float* __restrict__ w1,
    const float* __restrict__ w2, const float* __restrict__ w3,
    short* __restrict__ xqb,
    short* __restrict__ d0, short* __restrict__ d1,
    short* __restrict__ d2, short* __restrict__ d3,
    const float* __restrict__ mkv, short* __restrict__ kall,
    short* __restrict__ vall,
    const unsigned char* __restrict__ maskb, const int* __restrict__ mlen,
    const int* __restrict__ padv, unsigned char* __restrict__ mbits)
{
    __shared__ short T[64][72];
    const int bx = blockIdx.x;
    const int tid = threadIdx.x;

    if (bx < 4096) {
        // ---- elementwise f32 -> bf16, 8 elems/thread ----
        int idx = bx * 256 + tid;                 // [0, 1048576)
        const float* src; short* dst; int i;
        if (idx < 524288) { src = xq; dst = xqb; i = idx; }
        else {
            int sel = (idx >> 17) & 3;
            i = idx & 131071;
            src = sel == 0 ? w0 : sel == 1 ? w1 : sel == 2 ? w2 : w3;
            dst = sel == 0 ? d0 : sel == 1 ? d1 : sel == 2 ? d2 : d3;
        }
        const float4* s = (const float4*)src + (size_t)i * 2;
        float4 a = s[0], bq = s[1];
        short o[8];
        o[0] = f2bf(a.x);  o[1] = f2bf(a.y);  o[2] = f2bf(a.z);  o[3] = f2bf(a.w);
        o[4] = f2bf(bq.x); o[5] = f2bf(bq.y); o[6] = f2bf(bq.z); o[7] = f2bf(bq.w);
        *(uint4*)(dst + (size_t)i * 8) = *(uint4*)o;
        return;
    }

    if (bx < 7168) {
        // ---- mkv: [t][b][h][128] f32 -> kall[g][t][64] + vall[g][hc][t] ----
        const int idx = bx - 4096;                // [0, 3072)
        const int tc = idx % 24;
        const int h  = (idx / 24) & 15;
        const int b  = idx / 384;
        const int row = tid >> 2, part = tid & 3;
        const int t = tc * 64 + row;
        const int g = b * H_ + h;
        const float4* src = (const float4*)(mkv + (((size_t)t * B_ + b) * H_ + h) * 128 + part * 32);
        short o[32];
#pragma unroll
        for (int j = 0; j < 8; ++j) {
            float4 f = src[j];
            o[j * 4 + 0] = f2bf(f.x); o[j * 4 + 1] = f2bf(f.y);
            o[j * 4 + 2] = f2bf(f.z); o[j * 4 + 3] = f2bf(f.w);
        }
        if (part < 2) {   // K half: cols 0..63
            short* d = kall + ((size_t)g * TMX + t) * 64 + part * 32;
#pragma unroll
            for (int j = 0; j < 4; ++j) ((uint4*)d)[j] = ((uint4*)o)[j];
        } else {          // V half: cols 64..127 -> transpose via LDS
            int hc0 = (part - 2) * 32;
#pragma unroll
            for (int j = 0; j < 32; ++j) T[hc0 + j][row] = o[j];
        }
        __syncthreads();
        const int hc = tid >> 2, seg = tid & 3;
        uint4 a = *(const uint4*)&T[hc][seg * 16];
        uint4 c = *(const uint4*)&T[hc][seg * 16 + 8];
        short* d = vall + ((size_t)g * HC_ + hc) * TMX + tc * 64 + seg * 16;
        ((uint4*)d)[0] = a; ((uint4*)d)[1] = c;
        return;
    }

    if (bx < 7296) {
        // ---- zero vall garbage window readable by the last chunk ----
        const int i = bx - 7168;                  // [0, 128)
        const int b = i >> 4, h = i & 15;
        const int L = mlen[b], P = padv[b];
        const int te = L + P;
        const int z0 = max(1536, L + 512);
        const int z1 = min(2048, (te + 63) & ~63);
        if (z1 > z0) {
            const int g = b * 16 + h;
            const int hc = tid >> 2;
            short* rowp = vall + ((size_t)g * HC_ + hc) * TMX;
            for (int c = z0 + (tid & 3); c < z1; c += 4) rowp[c] = 0;
        }
        return;
    }

    // ---- maskBits: 2048 bits per (b,q) row (256 bytes). bit(t)=1 -> masked.
    //      t<L: 0 ; off>=P: 1 ; else user mask. One u64 word per thread:
    //      4096 rows x 32 words = 512 blocks x 256 threads. ----
    {
        const int j = bx - 7296;                  // [0, 512)
        const int b = j >> 6;
        const int q = (j & 63) * 8 + (tid >> 5);
        const int wordIdx = tid & 31;             // 64 t-values per word
        const int L = mlen[b], P = padv[b];
        const int tb = wordIdx * 64;
        unsigned long long w;
        if (tb + 63 < L) {
            w = 0ull;                              // fully in memory region
        } else if (tb >= L + P) {
            w = ~0ull;                             // fully past valid range
        } else {
            w = 0ull;
            const unsigned char* mq = maskb + (size_t)q * (KS_ * B_) + b;
#pragma unroll 4
            for (int k = 0; k < 64; ++k) {
                int t = tb + k;
                int bit;
                if (t < L) bit = 0;
                else {
                    int off = t - L;
                    bit = (off >= P) ? 1 : (mq[(size_t)off * B_] ? 1 : 0);
                }
                w |= (unsigned long long)bit << k;
            }
        }
        ((unsigned long long*)mbits)[(((size_t)(b * 512 + q)) << 5) + wordIdx] = w;
    }
}

// ---------------------------------------------------------------------------
// m97-style bf16 NT GEMM body: 128x128 tile, BK=64, global_load_lds width-16.
// oscale folds the attention temperature into the Q projection.
// KSC=true: epilogue scatters K directly into kall[(b*16+h)*TMX + L_b + s][hc]
// (same scalar-store pattern as a linear bf16 epilogue; saves the kbuf
// roundtrip and half of scatter_kv).
// ---------------------------------------------------------------------------
template <bool BF16OUT, bool KSC>
__device__ __forceinline__ void gemm128_body(
    short (*As)[64], short (*Ws)[64],
    const short* __restrict__ A, const short* __restrict__ W,
    const float* __restrict__ bias, void* __restrict__ outv,
    int n0, int j0, float oscale, const int* __restrict__ mlen)
{
    const int tid  = threadIdx.x;
    const int lane = tid & 63;
    const int wave = tid >> 6;
    const int wm = (wave & 1) * 64;
    const int wn = (wave >> 1) * 64;
    const int lr = lane & 15;
    const int quad = lane >> 4;

    f32x4 acc[4][4];
#pragma unroll
    for (int i = 0; i < 4; ++i)
#pragma unroll
        for (int j = 0; j < 4; ++j)
            acc[i][j] = (f32x4){0.f, 0.f, 0.f, 0.f};

    for (int k0 = 0; k0 < C_; k0 += 64) {
#pragma unroll
        for (int p = 0; p < 4; ++p) {
            int flat = p * 256 + tid;
            int r = flat >> 3, c8 = (flat & 7) * 8;
            gload_lds16(A + (size_t)(n0 + r) * C_ + k0 + c8, (short*)As + flat * 8);
        }
#pragma unroll
        for (int p = 0; p < 4; ++p) {
            int flat = p * 256 + tid;
            int r = flat >> 3, c8 = (flat & 7) * 8;
            gload_lds16(W + (size_t)(j0 + r) * C_ + k0 + c8, (short*)Ws + flat * 8);
        }
        __syncthreads();
#pragma unroll
        for (int ks = 0; ks < 2; ++ks) {
            const int kk = ks * 32 + quad * 8;
            bf16x8 afrag[4], bfrag[4];
#pragma unroll
            for (int im = 0; im < 4; ++im)
                afrag[im] = *(const bf16x8*)&As[wm + im * 16 + lr][kk];
#pragma unroll
            for (int jn = 0; jn < 4; ++jn)
                bfrag[jn] = *(const bf16x8*)&Ws[wn + jn * 16 + lr][kk];
#pragma unroll
            for (int im = 0; im < 4; ++im)
#pragma unroll
                for (int jn = 0; jn < 4; ++jn)
                    acc[im][jn] = __builtin_amdgcn_mfma_f32_16x16x32_bf16(
                        afrag[im], bfrag[jn], acc[im][jn], 0, 0, 0);
        }
        __syncthreads();
    }

    if constexpr (KSC) {
        int ml[8];
#pragma unroll
        for (int i = 0; i < 8; ++i) ml[i] = mlen[i];
#pragma unroll
        for (int jn = 0; jn < 4; ++jn) {
            const int col = j0 + wn + jn * 16 + lr;
            const int h = col >> 6, hc = col & 63;
            const float bv = bias[col];
#pragma unroll
            for (int im = 0; im < 4; ++im) {
                const int row = n0 + wm + im * 16 + quad * 4;
#pragma unroll
                for (int r = 0; r < 4; ++r) {
                    const int rr = row + r;
                    const int s = rr >> 3, b = rr & 7;
                    float v = acc[im][jn][r] + bv;
                    ((short*)outv)[((size_t)((b * 16 + h) * TMX) + ml[b] + s) * 64 + hc] = f2bf(v);
                }
            }
        }
    } else {
#pragma unroll
        for (int jn = 0; jn < 4; ++jn) {
            const int col = j0 + wn + jn * 16 + lr;
            const float bv = bias[col];
#pragma unroll
            for (int im = 0; im < 4; ++im) {
                const int row = n0 + wm + im * 16 + quad * 4;
#pragma unroll
                for (int r = 0; r < 4; ++r) {
                    float v = (acc[im][jn][r] + bv) * oscale;
                    if (BF16OUT)
                        ((short*)outv)[(size_t)(row + r) * C_ + col] = f2bf(v);
                    else
                        ((float*)outv)[(size_t)(row + r) * C_ + col] = v;
                }
            }
        }
    }
}

template <bool BF16OUT>
__global__ __launch_bounds__(256) void gemm128(
    const short* __restrict__ A, const short* __restrict__ W,
    const float* __restrict__ bias, void* __restrict__ outv)
{
    __shared__ short As[128][64];
    __shared__ short Ws[128][64];
    gemm128_body<BF16OUT, false>(As, Ws, A, W, bias, outv,
                                 blockIdx.x * 128, blockIdx.y * 128, 1.0f, nullptr);
}

// Fused Q/K/V projection: grid (32, 24). Q output pre-scaled by temperature;
// K output scattered straight into kall at absolute-t rows.
__global__ __launch_bounds__(256) void gemm128_qkv(
    const short* __restrict__ A,
    const short* __restrict__ Wq, const short* __restrict__ Wk,
    const short* __restrict__ Wv,
    const float* __restrict__ bq, const float* __restrict__ bk,
    const float* __restrict__ bv,
    short* __restrict__ oq, short* __restrict__ kall, short* __restrict__ ov,
    const int* __restrict__ mlen)
{
    __shared__ short As[128][64];
    __shared__ short Ws[128][64];
    const int sel = blockIdx.y >> 3;
    const int n0 = blockIdx.x * 128;
    const int j0 = (blockIdx.y & 7) * 128;
    if (sel == 0)
        gemm128_body<true, false>(As, Ws, A, Wq, bq, oq, n0, j0, 0.125f, nullptr);
    else if (sel == 1)
        gemm128_body<true, true>(As, Ws, A, Wk, bk, kall, n0, j0, 1.0f, mlen);
    else
        gemm128_body<true, false>(As, Ws, A, Wv, bv, ov, n0, j0, 1.0f, nullptr);
}

// ---------------------------------------------------------------------------
// Scatter new V into the merged absolute-t buffer (K handled in the GEMM).
// vbuf [s][b][C] -> vall[g][hc][L+s]  (LDS transpose, scalar stores)
// ---------------------------------------------------------------------------
__global__ __launch_bounds__(256) void scatter_kv(
    const short* __restrict__ vbuf, const int* __restrict__ mlen,
    short* __restrict__ vall)
{
    __shared__ short T[64][72];
    const int bx = blockIdx.x;
    const int tid = threadIdx.x;
    const int sc = bx & 7, h = (bx >> 3) & 15, b = bx >> 7;
    const int r = tid >> 2, seg = tid & 3;
    const int s = sc * 64 + r;
    const short* src = vbuf + ((size_t)s * B_ + b) * C_ + h * HC_ + seg * 16;
    short tmp[16];
    *(uint4*)&tmp[0] = ((const uint4*)src)[0];
    *(uint4*)&tmp[8] = ((const uint4*)src)[1];
#pragma unroll
    for (int j = 0; j < 16; ++j) T[seg * 16 + j][r] = tmp[j];
    __syncthreads();
    const int L = mlen[b];
    const int hc = tid >> 2;
    const int g = b * H_ + h;
    short* drow = vall + ((size_t)g * HC_ + hc) * TMX + L + sc * 64 + seg * 16;
    const short* srow = &T[hc][seg * 16];
#pragma unroll
    for (int j = 0; j < 16; ++j) drow[j] = srow[j];  // dst may be odd-aligned
}

// ---------------------------------------------------------------------------
// Flash attention, LDS-staged 2-phase pipeline.
// Block = (g, 64 q-rows); 4 waves x 16 q, barrier-synced over the shared
// t-chunk stream. K/V staged via global_load_lds into double-buffered,
// XOR-swizzled LDS (swizzle on the GLOBAL source, rule #21).
// Block mapping: g = ((bx>>6)<<3)|(bx&7), qg=(bx>>3)&7.
//   - same-XCD (bx%8) => same g low bits: one XCD serves 16 g-streams.
//   - co-resident blocks on one CU (stride-256 under round-robin dispatch)
//     differ in g by 32 => b by 2: each CU gets 4 distinct b (tend balance;
//     the old (bx+(bx>>3))&7 gave all 4 slots the SAME b -> 2x tail).
// Grid 1024 blocks, 32KB LDS -> 4 blocks/CU -> ALL blocks co-resident.
// ---------------------------------------------------------------------------
__global__ __launch_bounds__(256, 4) void attn_block(
    const short* __restrict__ qb, const short* __restrict__ kall,
    const short* __restrict__ vall, const unsigned char* __restrict__ mbits,
    const int* __restrict__ mlen, const int* __restrict__ padv,
    short* __restrict__ xout)
{
    __shared__ short Ks[2][64][64];   // [buf][t][hc], 128B rows, swizzled
    __shared__ short Vs[2][64][64];   // [buf][hc][t], 128B rows, swizzled

    const int tid  = threadIdx.x;
    const int lane = tid & 63;
    const int wave = tid >> 6;
    const int lr   = lane & 15;
    const int quad = lane >> 4;
    const int bx = blockIdx.x;
    const int g  = ((bx >> 6) << 3) | (bx & 7);
    const int qg = (bx >> 3) & 7;
    const int b  = g >> 4, h = g & 15;
    const int tend = mlen[b] + padv[b];
    const float NEG = -1e30f;

    const int q = qg * 64 + wave * 16 + lr;

    const short* qrow = qb + ((size_t)q * B_ + b) * C_ + h * HC_;
    bf16x8 q0 = *(const bf16x8*)(qrow + quad * 8);
    bf16x8 q1 = *(const bf16x8*)(qrow + 32 + quad * 8);

    const char* kg = (const char*)(kall + (size_t)g * TMX * 64);
    const char* vg = (const char*)(vall + (size_t)g * HC_ * TMX);
    const unsigned char* mrow = mbits + ((size_t)(b * 512 + q) << 8);  // 256B/row

    f32x4 O[4];
#pragma unroll
    for (int i = 0; i < 4; ++i) O[i] = (f32x4){0.f, 0.f, 0.f, 0.f};
    float mr = NEG, lsum = 0.f;

    const int nch = (tend + 63) >> 6;

    // Stage one chunk: waves 0,1 stage K (8KB), waves 2,3 stage V (8KB).
    // Dest is linear; source column pre-swizzled with c ^= ((row&7)<<4).
    auto stage = [&](int t0, int buf) {
        char* KsB = (char*)Ks[buf];
        char* VsB = (char*)Vs[buf];
#pragma unroll
        for (int i = 0; i < 4; ++i) {
            int p = wave * 4 + i;
            int f = ((p & 7) << 6) + lane;        // [0,512) 16B pieces
            int row = f >> 3;
            int c = ((f & 7) << 4) ^ ((row & 7) << 4);
            if (p < 8)
                gload_lds16(kg + (size_t)(t0 + row) * 128 + c,
                            KsB + (size_t)f * 16);
            else
                gload_lds16(vg + (size_t)row * (TMX * 2) + (size_t)t0 * 2 + c,
                            VsB + (size_t)f * 16);
        }
    };

    if (nch > 0) stage(0, 0);
    __syncthreads();

    int cur = 0;
    for (int ci = 0; ci < nch; ++ci) {
        const int t0 = ci << 6;

        // mask bits for this lane's q row, t in [t0, t0+64)
        unsigned long long mw = *(const unsigned long long*)(mrow + (t0 >> 3));

        // stage next chunk into the other buffer (drained by end barrier)
        if (ci + 1 < nch) stage((ci + 1) << 6, cur ^ 1);

        const char* KsB = (const char*)Ks[cur];
        const char* VsB = (const char*)Vs[cur];

        // ---- K fragments: A[m=t(lr)][k=hc(quad*8+j)] ----
        bf16x8 kf[4][2];
#pragma unroll
        for (int tt = 0; tt < 4; ++tt) {
            int t = tt * 16 + lr;
            int sw = (t & 7) << 4;
            kf[tt][0] = *(const bf16x8*)(KsB + t * 128 + ((quad * 16) ^ sw));
            kf[tt][1] = *(const bf16x8*)(KsB + t * 128 + ((64 + quad * 16) ^ sw));
        }

        // ---- S^T = K . Q^T ----
        __builtin_amdgcn_s_setprio(1);
        f32x4 S[4];
#pragma unroll
        for (int tt = 0; tt < 4; ++tt) {
            f32x4 z = (f32x4){0.f, 0.f, 0.f, 0.f};
            z = __builtin_amdgcn_mfma_f32_16x16x32_bf16(kf[tt][0], q0, z, 0, 0, 0);
            S[tt] = __builtin_amdgcn_mfma_f32_16x16x32_bf16(kf[tt][1], q1, z, 0, 0, 0);
        }
        __builtin_amdgcn_s_setprio(0);

        // ---- V fragments (LDS reads issued now, used at PV) ----
        bf16x8 vf[4][2];
#pragma unroll
        for (int ht = 0; ht < 4; ++ht) {
            int hc = ht * 16 + lr;
            int sw = (hc & 7) << 4;
            vf[ht][0] = *(const bf16x8*)(VsB + hc * 128 + ((quad * 16) ^ sw));
            vf[ht][1] = *(const bf16x8*)(VsB + hc * 128 + ((64 + quad * 16) ^ sw));
        }

        // ---- mask; lane value (tt,r) is (q, t=t0+tt*16+quad*4+r) ----
        float p4[4][4];
#pragma unroll
        for (int tt = 0; tt < 4; ++tt) {
            unsigned m4 = ((unsigned)(mw >> (tt * 16 + quad * 4))) & 15u;
#pragma unroll
            for (int r = 0; r < 4; ++r)
                p4[tt][r] = (m4 & (1u << r)) ? NEG : S[tt][r];
        }

        // ---- online softmax (cross-quad reduce via xor 16,32) ----
        float rm = NEG;
#pragma unroll
        for (int tt = 0; tt < 4; ++tt)
#pragma unroll
            for (int r = 0; r < 4; ++r) rm = fmaxf(rm, p4[tt][r]);
        rm = fmaxf(rm, __shfl_xor(rm, 16, 64));
        rm = fmaxf(rm, __shfl_xor(rm, 32, 64));
        const float nm = fmaxf(fmaxf(mr, rm), -1e20f);
        const float al = __expf(mr - nm);
        float rs = 0.f;
#pragma unroll
        for (int tt = 0; tt < 4; ++tt)
#pragma unroll
            for (int r = 0; r < 4; ++r) {
                float e = __expf(p4[tt][r] - nm);
                p4[tt][r] = e;
                rs += e;
            }
        rs += __shfl_xor(rs, 16, 64);
        rs += __shfl_xor(rs, 32, 64);
        lsum = lsum * al + rs;
        mr = nm;
#pragma unroll
        for (int ht = 0; ht < 4; ++ht)
#pragma unroll
            for (int r = 0; r < 4; ++r) O[ht][r] *= al;

        // ---- P^T fragments: pack to bf16 before shuffling ----
        bf16x8 pf[2];
        const int slA = ((quad & 1) * 2) * 16 + lr;
        const int slB = slA + 16;
        const unsigned sel = (quad & 2) ? 0x07060302u : 0x05040100u;
#pragma unroll
        for (int hf = 0; hf < 2; ++hf) {
            const int tt0 = hf * 2;
            unsigned pk[4];
#pragma unroll
            for (int r = 0; r < 4; ++r) {
                unsigned o;
                asm("v_cvt_pk_bf16_f32 %0, %1, %2"
                    : "=v"(o) : "v"(p4[tt0][r]), "v"(p4[tt0 + 1][r]));
                pk[r] = o;
            }
            unsigned uA[4], uB[4];
#pragma unroll
            for (int r = 0; r < 4; ++r) {
                uA[r] = (unsigned)__shfl((int)pk[r], slA, 64);
                uB[r] = (unsigned)__shfl((int)pk[r], slB, 64);
            }
            unsigned wv[4];
            wv[0] = __builtin_amdgcn_perm(uA[1], uA[0], sel);
            wv[1] = __builtin_amdgcn_perm(uA[3], uA[2], sel);
            wv[2] = __builtin_amdgcn_perm(uB[1], uB[0], sel);
            wv[3] = __builtin_amdgcn_perm(uB[3], uB[2], sel);
            pf[hf] = *(const bf16x8*)wv;
        }

        // ---- O^T += V^T . P^T ----
        __builtin_amdgcn_s_setprio(1);
#pragma unroll
        for (int ht = 0; ht < 4; ++ht) {
            O[ht] = __builtin_amdgcn_mfma_f32_16x16x32_bf16(vf[ht][0], pf[0], O[ht], 0, 0, 0);
            O[ht] = __builtin_amdgcn_mfma_f32_16x16x32_bf16(vf[ht][1], pf[1], O[ht], 0, 0, 0);
        }
        __builtin_amdgcn_s_setprio(0);

        __syncthreads();   // drains this iter's stage (vmcnt 0) + buffer reuse
        cur ^= 1;
    }

    // ---- epilogue: O^T row=hc=ht*16+quad*4+r, col=q ----
    float inv = (lsum > 0.f) ? 1.0f / lsum : 0.f;
#pragma unroll
    for (int ht = 0; ht < 4; ++ht) {
        short ov[4];
#pragma unroll
        for (int r = 0; r < 4; ++r) ov[r] = f2bf(O[ht][r] * inv);
        short* d = xout + ((size_t)q * B_ + b) * C_ + h * HC_ + ht * 16 + quad * 4;
        *(long long*)d = *(const long long*)ov;
    }
}

// ---------------------------------------------------------------------------
extern "C" void kernel_launch(void* const* d_in, const int* in_sizes, int n_in,
                              void* d_out, int out_size, void* d_ws, size_t ws_size,
                              hipStream_t stream)
{
    const float* xq   = (const float*)d_in[0];
    const int*   pad  = (const int*)d_in[1];
    const unsigned char* maskb = (const unsigned char*)d_in[2];
    const int*   mlen = (const int*)d_in[3];
    const float* mkv  = (const float*)d_in[4];
    const float* Wq   = (const float*)d_in[5];
    const float* bq   = (const float*)d_in[6];
    const float* Wk   = (const float*)d_in[7];
    const float* bk   = (const float*)d_in[8];
    const float* Wv   = (const float*)d_in[9];
    const float* bv   = (const float*)d_in[10];
    const float* Wo   = (const float*)d_in[11];
    const float* bo   = (const float*)d_in[12];
    float* out = (float*)d_out;

    // Workspace layout (shorts), ~105 MiB + 1 MiB mask bits
    short* xqb  = (short*)d_ws;
    short* wqb  = xqb  + (size_t)4194304;                 // 512*8*1024
    short* wkb  = wqb  + (size_t)1048576;
    short* wvb  = wkb  + (size_t)1048576;
    short* wob  = wvb  + (size_t)1048576;
    short* kall = wob  + (size_t)1048576;                 // 128*2048*64
    short* vall = kall + (size_t)128 * TMX * 64;          // 128*64*2048
    short* qbuf = vall + (size_t)128 * HC_ * TMX;
    short* vbuf = qbuf + (size_t)4194304;
    short* xbuf = vbuf + (size_t)4194304;
    unsigned char* mbits = (unsigned char*)(xbuf + (size_t)4194304); // 1MB

    dim3 gblk(256);
    // 1) converts + mkv merge-prep + V tail zero + mask bit build
    prep_all<<<dim3(7808), gblk, 0, stream>>>(
        xq, Wq, Wk, Wv, Wo, xqb, wqb, wkb, wvb, wob,
        mkv, kall, vall, maskb, mlen, pad, mbits);

    // 2) fused q/k/v projection (Q pre-scaled; K scattered into kall)
    gemm128_qkv<<<dim3(32, 24), gblk, 0, stream>>>(
        xqb, wqb, wkb, wvb, bq, bk, bv, qbuf, kall, vbuf, mlen);

    // 3) scatter new V into merged absolute-t buffer
    scatter_kv<<<dim3(1024), gblk, 0, stream>>>(vbuf, mlen, vall);

    // 4) LDS-staged flash attention (all 1024 blocks co-resident)
    attn_block<<<dim3(1024), gblk, 0, stream>>>(qbuf, kall, vall, mbits,
                                                mlen, pad, xbuf);

    // 5) output projection (f32 out)
    gemm128<false><<<dim3(32, 8), gblk, 0, stream>>>(xbuf, wob, bo, out);
}

// Round 7
// 332.941 us; speedup vs baseline: 1.7567x; 1.0387x over previous
//
#include <hip/hip_runtime.h>

// Problem constants (fixed by the reference's setup_inputs)
#define QS_ 512
#define B_  8
#define C_  1024
#define H_  16
#define HC_ 64
#define M_  1536
#define KS_ 512
#define TMX 2048   // merged K/V t-range: ceil((1535+511)/64)*64 = 2048

typedef __attribute__((ext_vector_type(8))) short bf16x8;
typedef __attribute__((ext_vector_type(4))) float f32x4;

__device__ __forceinline__ short f2bf(float f) {
    unsigned u = __float_as_uint(f);
    unsigned r = (u + 0x7FFF + ((u >> 16) & 1)) >> 16;   // RNE
    return (short)r;
}

__device__ __forceinline__ void gload_lds16(const void* g, void* l) {
    __builtin_amdgcn_global_load_lds(
        (const __attribute__((address_space(1))) unsigned int*)g,
        (__attribute__((address_space(3))) unsigned int*)l, 16, 0, 0);
}

// ---------------------------------------------------------------------------
// Fused prep, one launch, block ranges:
//  [0,4096)     : f32->bf16 converts (xq + 4 weights)
//  [4096,7168)  : memory_kv -> kall rows / vall cols, with two skips:
//                 (a) whole chunk if tc*64 >= L+P (never read by attention)
//                 (b) per-row [L, L+512): K-store+read skipped (the QKV GEMM
//                     epilogue overwrites kall rows and vall cols [L,L+512));
//                     V transpose stores garbage there, fully overwritten.
//  [7168,7296)  : zero vall tail window [max(1536,L+512), ceil64(L+P))
//  [7296,7808)  : build maskBits[b][q][2048 bits over absolute t] (256B/row)
// ---------------------------------------------------------------------------
__global__ __launch_bounds__(256) void prep_all(
    const float* __restrict__ xq,
    const float* __restrict__ w0, const float* __restrict__ w1,
    const float* __restrict__ w2, const float* __restrict__ w3,
    short* __restrict__ xqb,
    short* __restrict__ d0, short* __restrict__ d1,
    short* __restrict__ d2, short* __restrict__ d3,
    const float* __restrict__ mkv, short* __restrict__ kall,
    short* __restrict__ vall,
    const unsigned char* __restrict__ maskb, const int* __restrict__ mlen,
    const int* __restrict__ padv, unsigned char* __restrict__ mbits)
{
    __shared__ short T[64][72];
    const int bx = blockIdx.x;
    const int tid = threadIdx.x;

    if (bx < 4096) {
        // ---- elementwise f32 -> bf16, 8 elems/thread ----
        int idx = bx * 256 + tid;                 // [0, 1048576)
        const float* src; short* dst; int i;
        if (idx < 524288) { src = xq; dst = xqb; i = idx; }
        else {
            int sel = (idx >> 17) & 3;
            i = idx & 131071;
            src = sel == 0 ? w0 : sel == 1 ? w1 : sel == 2 ? w2 : w3;
            dst = sel == 0 ? d0 : sel == 1 ? d1 : sel == 2 ? d2 : d3;
        }
        const float4* s = (const float4*)src + (size_t)i * 2;
        float4 a = s[0], bq = s[1];
        short o[8];
        o[0] = f2bf(a.x);  o[1] = f2bf(a.y);  o[2] = f2bf(a.z);  o[3] = f2bf(a.w);
        o[4] = f2bf(bq.x); o[5] = f2bf(bq.y); o[6] = f2bf(bq.z); o[7] = f2bf(bq.w);
        *(uint4*)(dst + (size_t)i * 8) = *(uint4*)o;
        return;
    }

    if (bx < 7168) {
        // ---- mkv: [t][b][h][128] f32 -> kall[g][t][64] + vall[g][hc][t] ----
        const int idx = bx - 4096;                // [0, 3072)
        const int tc = idx % 24;
        const int h  = (idx / 24) & 15;
        const int b  = idx / 384;
        const int L = mlen[b];
        const int tendb = L + padv[b];
        if (tc * 64 >= tendb) return;             // (a) chunk never read
        const int row = tid >> 2, part = tid & 3;
        const int t = tc * 64 + row;
        const int g = b * H_ + h;
        const bool skiprow = (t >= L) && (t < L + 512);   // (b) overwritten
        short o[32];
        if (!skiprow) {
            const float4* src = (const float4*)(mkv + (((size_t)t * B_ + b) * H_ + h) * 128 + part * 32);
#pragma unroll
            for (int j = 0; j < 8; ++j) {
                float4 f = src[j];
                o[j * 4 + 0] = f2bf(f.x); o[j * 4 + 1] = f2bf(f.y);
                o[j * 4 + 2] = f2bf(f.z); o[j * 4 + 3] = f2bf(f.w);
            }
        } else {
#pragma unroll
            for (int j = 0; j < 32; ++j) o[j] = 0;
        }
        if (part < 2) {   // K half: cols 0..63
            if (!skiprow) {
                short* d = kall + ((size_t)g * TMX + t) * 64 + part * 32;
#pragma unroll
                for (int j = 0; j < 4; ++j) ((uint4*)d)[j] = ((uint4*)o)[j];
            }
        } else {          // V half: cols 64..127 -> transpose via LDS
            int hc0 = (part - 2) * 32;
#pragma unroll
            for (int j = 0; j < 32; ++j) T[hc0 + j][row] = o[j];
        }
        __syncthreads();
        const int hc = tid >> 2, seg = tid & 3;
        uint4 a = *(const uint4*)&T[hc][seg * 16];
        uint4 c = *(const uint4*)&T[hc][seg * 16 + 8];
        short* d = vall + ((size_t)g * HC_ + hc) * TMX + tc * 64 + seg * 16;
        ((uint4*)d)[0] = a; ((uint4*)d)[1] = c;
        return;
    }

    if (bx < 7296) {
        // ---- zero vall garbage window readable by the last chunk ----
        const int i = bx - 7168;                  // [0, 128)
        const int b = i >> 4, h = i & 15;
        const int L = mlen[b], P = padv[b];
        const int te = L + P;
        const int z0 = max(1536, L + 512);
        const int z1 = min(2048, (te + 63) & ~63);
        if (z1 > z0) {
            const int g = b * 16 + h;
            const int hc = tid >> 2;
            short* rowp = vall + ((size_t)g * HC_ + hc) * TMX;
            for (int c = z0 + (tid & 3); c < z1; c += 4) rowp[c] = 0;
        }
        return;
    }

    // ---- maskBits: 2048 bits per (b,q) row (256 bytes). bit(t)=1 -> masked.
    //      t<L: 0 ; off>=P: 1 ; else user mask. One u64 word per thread:
    //      4096 rows x 32 words = 512 blocks x 256 threads. ----
    {
        const int j = bx - 7296;                  // [0, 512)
        const int b = j >> 6;
        const int q = (j & 63) * 8 + (tid >> 5);
        const int wordIdx = tid & 31;             // 64 t-values per word
        const int L = mlen[b], P = padv[b];
        const int tb = wordIdx * 64;
        unsigned long long w;
        if (tb + 63 < L) {
            w = 0ull;                              // fully in memory region
        } else if (tb >= L + P) {
            w = ~0ull;                             // fully past valid range
        } else {
            w = 0ull;
            const unsigned char* mq = maskb + (size_t)q * (KS_ * B_) + b;
#pragma unroll 4
            for (int k = 0; k < 64; ++k) {
                int t = tb + k;
                int bit;
                if (t < L) bit = 0;
                else {
                    int off = t - L;
                    bit = (off >= P) ? 1 : (mq[(size_t)off * B_] ? 1 : 0);
                }
                w |= (unsigned long long)bit << k;
            }
        }
        ((unsigned long long*)mbits)[(((size_t)(b * 512 + q)) << 5) + wordIdx] = w;
    }
}

// ---------------------------------------------------------------------------
// m97-style bf16 NT GEMM body: 128x128 tile, BK=64, global_load_lds width-16.
// EPI: 0 = f32 linear; 1 = bf16 linear (oscale folds Q temperature);
//      2 = K scatter into kall[(b*16+h)*TMX + L_b + s][hc];
//      3 = V transposed scatter into vall[((b*16+h)*64+hc)*TMX + L_b + s].
// ---------------------------------------------------------------------------
template <int EPI>
__device__ __forceinline__ void gemm128_body(
    short (*As)[64], short (*Ws)[64],
    const short* __restrict__ A, const short* __restrict__ W,
    const float* __restrict__ bias, void* __restrict__ outv,
    int n0, int j0, float oscale, const int* __restrict__ mlen)
{
    const int tid  = threadIdx.x;
    const int lane = tid & 63;
    const int wave = tid >> 6;
    const int wm = (wave & 1) * 64;
    const int wn = (wave >> 1) * 64;
    const int lr = lane & 15;
    const int quad = lane >> 4;

    f32x4 acc[4][4];
#pragma unroll
    for (int i = 0; i < 4; ++i)
#pragma unroll
        for (int j = 0; j < 4; ++j)
            acc[i][j] = (f32x4){0.f, 0.f, 0.f, 0.f};

    for (int k0 = 0; k0 < C_; k0 += 64) {
#pragma unroll
        for (int p = 0; p < 4; ++p) {
            int flat = p * 256 + tid;
            int r = flat >> 3, c8 = (flat & 7) * 8;
            gload_lds16(A + (size_t)(n0 + r) * C_ + k0 + c8, (short*)As + flat * 8);
        }
#pragma unroll
        for (int p = 0; p < 4; ++p) {
            int flat = p * 256 + tid;
            int r = flat >> 3, c8 = (flat & 7) * 8;
            gload_lds16(W + (size_t)(j0 + r) * C_ + k0 + c8, (short*)Ws + flat * 8);
        }
        __syncthreads();
#pragma unroll
        for (int ks = 0; ks < 2; ++ks) {
            const int kk = ks * 32 + quad * 8;
            bf16x8 afrag[4], bfrag[4];
#pragma unroll
            for (int im = 0; im < 4; ++im)
                afrag[im] = *(const bf16x8*)&As[wm + im * 16 + lr][kk];
#pragma unroll
            for (int jn = 0; jn < 4; ++jn)
                bfrag[jn] = *(const bf16x8*)&Ws[wn + jn * 16 + lr][kk];
#pragma unroll
            for (int im = 0; im < 4; ++im)
#pragma unroll
                for (int jn = 0; jn < 4; ++jn)
                    acc[im][jn] = __builtin_amdgcn_mfma_f32_16x16x32_bf16(
                        afrag[im], bfrag[jn], acc[im][jn], 0, 0, 0);
        }
        __syncthreads();
    }

    if constexpr (EPI == 2 || EPI == 3) {
        int ml[8];
#pragma unroll
        for (int i = 0; i < 8; ++i) ml[i] = mlen[i];
#pragma unroll
        for (int jn = 0; jn < 4; ++jn) {
            const int col = j0 + wn + jn * 16 + lr;
            const int h = col >> 6, hc = col & 63;
            const float bv = bias[col];
#pragma unroll
            for (int im = 0; im < 4; ++im) {
                const int row = n0 + wm + im * 16 + quad * 4;
#pragma unroll
                for (int r = 0; r < 4; ++r) {
                    const int rr = row + r;
                    const int s = rr >> 3, b = rr & 7;
                    float v = acc[im][jn][r] + bv;
                    if (EPI == 2)        // K: row t = L+s, dense hc
                        ((short*)outv)[((size_t)((b * 16 + h) * TMX) + ml[b] + s) * 64 + hc] = f2bf(v);
                    else                 // V: row hc, col t = L+s
                        ((short*)outv)[((size_t)((b * 16 + h) * 64 + hc)) * TMX + ml[b] + s] = f2bf(v);
                }
            }
        }
    } else {
#pragma unroll
        for (int jn = 0; jn < 4; ++jn) {
            const int col = j0 + wn + jn * 16 + lr;
            const float bv = bias[col];
#pragma unroll
            for (int im = 0; im < 4; ++im) {
                const int row = n0 + wm + im * 16 + quad * 4;
#pragma unroll
                for (int r = 0; r < 4; ++r) {
                    float v = (acc[im][jn][r] + bv) * oscale;
                    if (EPI == 1)
                        ((short*)outv)[(size_t)(row + r) * C_ + col] = f2bf(v);
                    else
                        ((float*)outv)[(size_t)(row + r) * C_ + col] = v;
                }
            }
        }
    }
}

__global__ __launch_bounds__(256) void gemm128_f32(
    const short* __restrict__ A, const short* __restrict__ W,
    const float* __restrict__ bias, float* __restrict__ outv)
{
    __shared__ short As[128][64];
    __shared__ short Ws[128][64];
    gemm128_body<0>(As, Ws, A, W, bias, outv,
                    blockIdx.x * 128, blockIdx.y * 128, 1.0f, nullptr);
}

// Fused Q/K/V projection: grid (32, 24). Q pre-scaled by temperature to qbuf;
// K scattered into kall rows [L, L+512); V transpose-scattered into vall
// cols [L, L+512) (replaces the old scatter_kv kernel + vbuf roundtrip).
__global__ __launch_bounds__(256) void gemm128_qkv(
    const short* __restrict__ A,
    const short* __restrict__ Wq, const short* __restrict__ Wk,
    const short* __restrict__ Wv,
    const float* __restrict__ bq, const float* __restrict__ bk,
    const float* __restrict__ bv,
    short* __restrict__ oq, short* __restrict__ kall, short* __restrict__ vall,
    const int* __restrict__ mlen)
{
    __shared__ short As[128][64];
    __shared__ short Ws[128][64];
    const int sel = blockIdx.y >> 3;
    const int n0 = blockIdx.x * 128;
    const int j0 = (blockIdx.y & 7) * 128;
    if (sel == 0)
        gemm128_body<1>(As, Ws, A, Wq, bq, oq, n0, j0, 0.125f, nullptr);
    else if (sel == 1)
        gemm128_body<2>(As, Ws, A, Wk, bk, kall, n0, j0, 1.0f, mlen);
    else
        gemm128_body<3>(As, Ws, A, Wv, bv, vall, n0, j0, 1.0f, mlen);
}

// ---------------------------------------------------------------------------
// Flash attention, LDS-staged 2-phase pipeline.
// Block = (g, 64 q-rows); 4 waves x 16 q, barrier-synced over the shared
// t-chunk stream. K/V staged via global_load_lds into double-buffered,
// XOR-swizzled LDS (swizzle on the GLOBAL source, rule #21).
// Block mapping: g = ((bx>>6)<<3)|(bx&7), qg=(bx>>3)&7.
//   - same-XCD (bx%8) => same g low bits: one XCD serves 16 g-streams.
//   - co-resident blocks on one CU (stride-256 under round-robin dispatch)
//     differ in g by 32 => b by 2: each CU gets 4 distinct b (tend balance).
// Grid 1024 blocks, 32KB LDS -> 4 blocks/CU -> ALL blocks co-resident.
// ---------------------------------------------------------------------------
__global__ __launch_bounds__(256, 4) void attn_block(
    const short* __restrict__ qb, const short* __restrict__ kall,
    const short* __restrict__ vall, const unsigned char* __restrict__ mbits,
    const int* __restrict__ mlen, const int* __restrict__ padv,
    short* __restrict__ xout)
{
    __shared__ short Ks[2][64][64];   // [buf][t][hc], 128B rows, swizzled
    __shared__ short Vs[2][64][64];   // [buf][hc][t], 128B rows, swizzled

    const int tid  = threadIdx.x;
    const int lane = tid & 63;
    const int wave = tid >> 6;
    const int lr   = lane & 15;
    const int quad = lane >> 4;
    const int bx = blockIdx.x;
    const int g  = ((bx >> 6) << 3) | (bx & 7);
    const int qg = (bx >> 3) & 7;
    const int b  = g >> 4, h = g & 15;
    const int tend = mlen[b] + padv[b];
    const float NEG = -1e30f;

    const int q = qg * 64 + wave * 16 + lr;

    const short* qrow = qb + ((size_t)q * B_ + b) * C_ + h * HC_;
    bf16x8 q0 = *(const bf16x8*)(qrow + quad * 8);
    bf16x8 q1 = *(const bf16x8*)(qrow + 32 + quad * 8);

    const char* kg = (const char*)(kall + (size_t)g * TMX * 64);
    const char* vg = (const char*)(vall + (size_t)g * HC_ * TMX);
    const unsigned char* mrow = mbits + ((size_t)(b * 512 + q) << 8);  // 256B/row

    f32x4 O[4];
#pragma unroll
    for (int i = 0; i < 4; ++i) O[i] = (f32x4){0.f, 0.f, 0.f, 0.f};
    float mr = NEG, lsum = 0.f;

    const int nch = (tend + 63) >> 6;

    // Stage one chunk: waves 0,1 stage K (8KB), waves 2,3 stage V (8KB).
    // Dest is linear; source column pre-swizzled with c ^= ((row&7)<<4).
    auto stage = [&](int t0, int buf) {
        char* KsB = (char*)Ks[buf];
        char* VsB = (char*)Vs[buf];
#pragma unroll
        for (int i = 0; i < 4; ++i) {
            int p = wave * 4 + i;
            int f = ((p & 7) << 6) + lane;        // [0,512) 16B pieces
            int row = f >> 3;
            int c = ((f & 7) << 4) ^ ((row & 7) << 4);
            if (p < 8)
                gload_lds16(kg + (size_t)(t0 + row) * 128 + c,
                            KsB + (size_t)f * 16);
            else
                gload_lds16(vg + (size_t)row * (TMX * 2) + (size_t)t0 * 2 + c,
                            VsB + (size_t)f * 16);
        }
    };

    if (nch > 0) stage(0, 0);
    __syncthreads();

    int cur = 0;
    for (int ci = 0; ci < nch; ++ci) {
        const int t0 = ci << 6;

        // mask bits for this lane's q row, t in [t0, t0+64)
        unsigned long long mw = *(const unsigned long long*)(mrow + (t0 >> 3));

        // stage next chunk into the other buffer (drained by end barrier)
        if (ci + 1 < nch) stage((ci + 1) << 6, cur ^ 1);

        const char* KsB = (const char*)Ks[cur];
        const char* VsB = (const char*)Vs[cur];

        // ---- K fragments: A[m=t(lr)][k=hc(quad*8+j)] ----
        bf16x8 kf[4][2];
#pragma unroll
        for (int tt = 0; tt < 4; ++tt) {
            int t = tt * 16 + lr;
            int sw = (t & 7) << 4;
            kf[tt][0] = *(const bf16x8*)(KsB + t * 128 + ((quad * 16) ^ sw));
            kf[tt][1] = *(const bf16x8*)(KsB + t * 128 + ((64 + quad * 16) ^ sw));
        }

        // ---- S^T = K . Q^T ----
        __builtin_amdgcn_s_setprio(1);
        f32x4 S[4];
#pragma unroll
        for (int tt = 0; tt < 4; ++tt) {
            f32x4 z = (f32x4){0.f, 0.f, 0.f, 0.f};
            z = __builtin_amdgcn_mfma_f32_16x16x32_bf16(kf[tt][0], q0, z, 0, 0, 0);
            S[tt] = __builtin_amdgcn_mfma_f32_16x16x32_bf16(kf[tt][1], q1, z, 0, 0, 0);
        }
        __builtin_amdgcn_s_setprio(0);

        // ---- V fragments (LDS reads issued now, used at PV) ----
        bf16x8 vf[4][2];
#pragma unroll
        for (int ht = 0; ht < 4; ++ht) {
            int hc = ht * 16 + lr;
            int sw = (hc & 7) << 4;
            vf[ht][0] = *(const bf16x8*)(VsB + hc * 128 + ((quad * 16) ^ sw));
            vf[ht][1] = *(const bf16x8*)(VsB + hc * 128 + ((64 + quad * 16) ^ sw));
        }

        // ---- mask; lane value (tt,r) is (q, t=t0+tt*16+quad*4+r) ----
        float p4[4][4];
#pragma unroll
        for (int tt = 0; tt < 4; ++tt) {
            unsigned m4 = ((unsigned)(mw >> (tt * 16 + quad * 4))) & 15u;
#pragma unroll
            for (int r = 0; r < 4; ++r)
                p4[tt][r] = (m4 & (1u << r)) ? NEG : S[tt][r];
        }

        // ---- online softmax (cross-quad reduce via xor 16,32) ----
        float rm = NEG;
#pragma unroll
        for (int tt = 0; tt < 4; ++tt)
#pragma unroll
            for (int r = 0; r < 4; ++r) rm = fmaxf(rm, p4[tt][r]);
        rm = fmaxf(rm, __shfl_xor(rm, 16, 64));
        rm = fmaxf(rm, __shfl_xor(rm, 32, 64));
        const float nm = fmaxf(fmaxf(mr, rm), -1e20f);
        const float al = __expf(mr - nm);
        float rs = 0.f;
#pragma unroll
        for (int tt = 0; tt < 4; ++tt)
#pragma unroll
            for (int r = 0; r < 4; ++r) {
                float e = __expf(p4[tt][r] - nm);
                p4[tt][r] = e;
                rs += e;
            }
        rs += __shfl_xor(rs, 16, 64);
        rs += __shfl_xor(rs, 32, 64);
        lsum = lsum * al + rs;
        mr = nm;
#pragma unroll
        for (int ht = 0; ht < 4; ++ht)
#pragma unroll
            for (int r = 0; r < 4; ++r) O[ht][r] *= al;

        // ---- P^T fragments: pack to bf16 before shuffling ----
        bf16x8 pf[2];
        const int slA = ((quad & 1) * 2) * 16 + lr;
        const int slB = slA + 16;
        const unsigned sel = (quad & 2) ? 0x07060302u : 0x05040100u;
#pragma unroll
        for (int hf = 0; hf < 2; ++hf) {
            const int tt0 = hf * 2;
            unsigned pk[4];
#pragma unroll
            for (int r = 0; r < 4; ++r) {
                unsigned o;
                asm("v_cvt_pk_bf16_f32 %0, %1, %2"
                    : "=v"(o) : "v"(p4[tt0][r]), "v"(p4[tt0 + 1][r]));
                pk[r] = o;
            }
            unsigned uA[4], uB[4];
#pragma unroll
            for (int r = 0; r < 4; ++r) {
                uA[r] = (unsigned)__shfl((int)pk[r], slA, 64);
                uB[r] = (unsigned)__shfl((int)pk[r], slB, 64);
            }
            unsigned wv[4];
            wv[0] = __builtin_amdgcn_perm(uA[1], uA[0], sel);
            wv[1] = __builtin_amdgcn_perm(uA[3], uA[2], sel);
            wv[2] = __builtin_amdgcn_perm(uB[1], uB[0], sel);
            wv[3] = __builtin_amdgcn_perm(uB[3], uB[2], sel);
            pf[hf] = *(const bf16x8*)wv;
        }

        // ---- O^T += V^T . P^T ----
        __builtin_amdgcn_s_setprio(1);
#pragma unroll
        for (int ht = 0; ht < 4; ++ht) {
            O[ht] = __builtin_amdgcn_mfma_f32_16x16x32_bf16(vf[ht][0], pf[0], O[ht], 0, 0, 0);
            O[ht] = __builtin_amdgcn_mfma_f32_16x16x32_bf16(vf[ht][1], pf[1], O[ht], 0, 0, 0);
        }
        __builtin_amdgcn_s_setprio(0);

        __syncthreads();   // drains this iter's stage (vmcnt 0) + buffer reuse
        cur ^= 1;
    }

    // ---- epilogue: O^T row=hc=ht*16+quad*4+r, col=q ----
    float inv = (lsum > 0.f) ? 1.0f / lsum : 0.f;
#pragma unroll
    for (int ht = 0; ht < 4; ++ht) {
        short ov[4];
#pragma unroll
        for (int r = 0; r < 4; ++r) ov[r] = f2bf(O[ht][r] * inv);
        short* d = xout + ((size_t)q * B_ + b) * C_ + h * HC_ + ht * 16 + quad * 4;
        *(long long*)d = *(const long long*)ov;
    }
}

// ---------------------------------------------------------------------------
extern "C" void kernel_launch(void* const* d_in, const int* in_sizes, int n_in,
                              void* d_out, int out_size, void* d_ws, size_t ws_size,
                              hipStream_t stream)
{
    const float* xq   = (const float*)d_in[0];
    const int*   pad  = (const int*)d_in[1];
    const unsigned char* maskb = (const unsigned char*)d_in[2];
    const int*   mlen = (const int*)d_in[3];
    const float* mkv  = (const float*)d_in[4];
    const float* Wq   = (const float*)d_in[5];
    const float* bq   = (const float*)d_in[6];
    const float* Wk   = (const float*)d_in[7];
    const float* bk   = (const float*)d_in[8];
    const float* Wv   = (const float*)d_in[9];
    const float* bv   = (const float*)d_in[10];
    const float* Wo   = (const float*)d_in[11];
    const float* bo   = (const float*)d_in[12];
    float* out = (float*)d_out;

    // Workspace layout (shorts), ~97 MiB + 1 MiB mask bits
    short* xqb  = (short*)d_ws;
    short* wqb  = xqb  + (size_t)4194304;                 // 512*8*1024
    short* wkb  = wqb  + (size_t)1048576;
    short* wvb  = wkb  + (size_t)1048576;
    short* wob  = wvb  + (size_t)1048576;
    short* kall = wob  + (size_t)1048576;                 // 128*2048*64
    short* vall = kall + (size_t)128 * TMX * 64;          // 128*64*2048
    short* qbuf = vall + (size_t)128 * HC_ * TMX;
    short* xbuf = qbuf + (size_t)4194304;
    unsigned char* mbits = (unsigned char*)(xbuf + (size_t)4194304); // 1MB

    dim3 gblk(256);
    // 1) converts + mkv merge-prep (skip dead rows) + V tail zero + mask bits
    prep_all<<<dim3(7808), gblk, 0, stream>>>(
        xq, Wq, Wk, Wv, Wo, xqb, wqb, wkb, wvb, wob,
        mkv, kall, vall, maskb, mlen, pad, mbits);

    // 2) fused q/k/v projection (Q pre-scaled; K,V scattered into kall/vall)
    gemm128_qkv<<<dim3(32, 24), gblk, 0, stream>>>(
        xqb, wqb, wkb, wvb, bq, bk, bv, qbuf, kall, vall, mlen);

    // 3) LDS-staged flash attention (all 1024 blocks co-resident)
    attn_block<<<dim3(1024), gblk, 0, stream>>>(qbuf, kall, vall, mbits,
                                                mlen, pad, xbuf);

    // 4) output projection (f32 out)
    gemm128_f32<<<dim3(32, 8), gblk, 0, stream>>>(xbuf, wob, bo, out);
}

// Round 8
// 303.593 us; speedup vs baseline: 1.9265x; 1.0967x over previous
//
#include <hip/hip_runtime.h>

// Problem constants (fixed by the reference's setup_inputs)
#define QS_ 512
#define B_  8
#define C_  1024
#define H_  16
#define HC_ 64
#define M_  1536
#define KS_ 512
#define TMX 2048   // merged K/V t-range: ceil((1535+511)/64)*64 = 2048

typedef __attribute__((ext_vector_type(8))) short bf16x8;
typedef __attribute__((ext_vector_type(4))) float f32x4;

__device__ __forceinline__ short f2bf(float f) {
    unsigned u = __float_as_uint(f);
    unsigned r = (u + 0x7FFF + ((u >> 16) & 1)) >> 16;   // RNE
    return (short)r;
}

__device__ __forceinline__ void gload_lds16(const void* g, void* l) {
    __builtin_amdgcn_global_load_lds(
        (const __attribute__((address_space(1))) unsigned int*)g,
        (__attribute__((address_space(3))) unsigned int*)l, 16, 0, 0);
}

// ---------------------------------------------------------------------------
// Converts only: f32->bf16 for xq + 4 weight matrices. 4096 blocks.
// Must finish before the QKV GEMM reads xqb/weights.
// ---------------------------------------------------------------------------
__global__ __launch_bounds__(256) void prep_cvt(
    const float* __restrict__ xq,
    const float* __restrict__ w0, const float* __restrict__ w1,
    const float* __restrict__ w2, const float* __restrict__ w3,
    short* __restrict__ xqb,
    short* __restrict__ d0, short* __restrict__ d1,
    short* __restrict__ d2, short* __restrict__ d3)
{
    int idx = blockIdx.x * 256 + threadIdx.x;     // [0, 1048576)
    const float* src; short* dst; int i;
    if (idx < 524288) { src = xq; dst = xqb; i = idx; }
    else {
        int sel = (idx >> 17) & 3;
        i = idx & 131071;
        src = sel == 0 ? w0 : sel == 1 ? w1 : sel == 2 ? w2 : w3;
        dst = sel == 0 ? d0 : sel == 1 ? d1 : sel == 2 ? d2 : d3;
    }
    const float4* s = (const float4*)src + (size_t)i * 2;
    float4 a = s[0], bq = s[1];
    short o[8];
    o[0] = f2bf(a.x);  o[1] = f2bf(a.y);  o[2] = f2bf(a.z);  o[3] = f2bf(a.w);
    o[4] = f2bf(bq.x); o[5] = f2bf(bq.y); o[6] = f2bf(bq.z); o[7] = f2bf(bq.w);
    *(uint4*)(dst + (size_t)i * 8) = *(uint4*)o;
}

// ---------------------------------------------------------------------------
// m97-style bf16 NT GEMM body: 128x128 tile, BK=64, global_load_lds width-16,
// T2 XOR-swizzled LDS (source col pre-swizzled, fragment reads XOR back;
// kills the 16-lane/bank conflict on ds_read_b128 of stride-128B rows).
// EPI: 0 = f32 linear; 1 = bf16 linear (oscale folds Q temperature);
//      2 = K scatter into kall[(b*16+h)*TMX + L_b + s][hc];
//      3 = V transposed scatter into vall[((b*16+h)*64+hc)*TMX + L_b + s].
// ---------------------------------------------------------------------------
template <int EPI>
__device__ __forceinline__ void gemm128_body(
    short (*As)[64], short (*Ws)[64],
    const short* __restrict__ A, const short* __restrict__ W,
    const float* __restrict__ bias, void* __restrict__ outv,
    int n0, int j0, float oscale, const int* __restrict__ mlen)
{
    const int tid  = threadIdx.x;
    const int lane = tid & 63;
    const int wave = tid >> 6;
    const int wm = (wave & 1) * 64;
    const int wn = (wave >> 1) * 64;
    const int lr = lane & 15;
    const int quad = lane >> 4;

    f32x4 acc[4][4];
#pragma unroll
    for (int i = 0; i < 4; ++i)
#pragma unroll
        for (int j = 0; j < 4; ++j)
            acc[i][j] = (f32x4){0.f, 0.f, 0.f, 0.f};

    for (int k0 = 0; k0 < C_; k0 += 64) {
#pragma unroll
        for (int p = 0; p < 4; ++p) {
            int flat = p * 256 + tid;
            int r = flat >> 3;
            int c8 = ((flat & 7) ^ (r & 7)) * 8;   // swizzled source col (shorts)
            gload_lds16(A + (size_t)(n0 + r) * C_ + k0 + c8, (short*)As + flat * 8);
        }
#pragma unroll
        for (int p = 0; p < 4; ++p) {
            int flat = p * 256 + tid;
            int r = flat >> 3;
            int c8 = ((flat & 7) ^ (r & 7)) * 8;
            gload_lds16(W + (size_t)(j0 + r) * C_ + k0 + c8, (short*)Ws + flat * 8);
        }
        __syncthreads();
#pragma unroll
        for (int ks = 0; ks < 2; ++ks) {
            const int kkb = (ks * 32 + quad * 8) * 2;   // byte offset pre-XOR
            bf16x8 afrag[4], bfrag[4];
#pragma unroll
            for (int im = 0; im < 4; ++im) {
                int row = wm + im * 16 + lr;
                afrag[im] = *(const bf16x8*)((const char*)As + row * 128 + (kkb ^ ((row & 7) << 4)));
            }
#pragma unroll
            for (int jn = 0; jn < 4; ++jn) {
                int row = wn + jn * 16 + lr;
                bfrag[jn] = *(const bf16x8*)((const char*)Ws + row * 128 + (kkb ^ ((row & 7) << 4)));
            }
#pragma unroll
            for (int im = 0; im < 4; ++im)
#pragma unroll
                for (int jn = 0; jn < 4; ++jn)
                    acc[im][jn] = __builtin_amdgcn_mfma_f32_16x16x32_bf16(
                        afrag[im], bfrag[jn], acc[im][jn], 0, 0, 0);
        }
        __syncthreads();
    }

    if constexpr (EPI == 2 || EPI == 3) {
        int ml[8];
#pragma unroll
        for (int i = 0; i < 8; ++i) ml[i] = mlen[i];
#pragma unroll
        for (int jn = 0; jn < 4; ++jn) {
            const int col = j0 + wn + jn * 16 + lr;
            const int h = col >> 6, hc = col & 63;
            const float bv = bias[col];
#pragma unroll
            for (int im = 0; im < 4; ++im) {
                const int row = n0 + wm + im * 16 + quad * 4;
#pragma unroll
                for (int r = 0; r < 4; ++r) {
                    const int rr = row + r;
                    const int s = rr >> 3, b = rr & 7;
                    float v = acc[im][jn][r] + bv;
                    if (EPI == 2)        // K: row t = L+s, dense hc
                        ((short*)outv)[((size_t)((b * 16 + h) * TMX) + ml[b] + s) * 64 + hc] = f2bf(v);
                    else                 // V: row hc, col t = L+s
                        ((short*)outv)[((size_t)((b * 16 + h) * 64 + hc)) * TMX + ml[b] + s] = f2bf(v);
                }
            }
        }
    } else {
#pragma unroll
        for (int jn = 0; jn < 4; ++jn) {
            const int col = j0 + wn + jn * 16 + lr;
            const float bv = bias[col];
#pragma unroll
            for (int im = 0; im < 4; ++im) {
                const int row = n0 + wm + im * 16 + quad * 4;
#pragma unroll
                for (int r = 0; r < 4; ++r) {
                    float v = (acc[im][jn][r] + bv) * oscale;
                    if (EPI == 1)
                        ((short*)outv)[(size_t)(row + r) * C_ + col] = f2bf(v);
                    else
                        ((float*)outv)[(size_t)(row + r) * C_ + col] = v;
                }
            }
        }
    }
}

// ---------------------------------------------------------------------------
// Fused QKV projection + memory-KV prep + V-tail zero + mask-bit build.
// Block ranges (GEMM first so it dispatches ahead; prep blocks backfill the
// ~75% of the machine the latency-bound GEMM leaves idle):
//  [0,768)      : QKV GEMM. sel=bx>>8; within: n0=((bx&255)>>3)*128,
//                 j0=(bx&7)*128. Q->qbuf (x0.125), K->kall, V->vall scatter.
//  [768,3840)   : memory_kv -> kall rows / vall cols. RACE-FIX vs old serial
//                 version: V stores SKIP cols in [L,L+512) (GEMM writes them
//                 concurrently); straddle windows store element-wise.
//  [3840,3968)  : zero vall tail window [max(1536,L+512), ceil64(L+P))
//  [3968,4480)  : maskBits[b][q][2048 bits] (256B/row)
// ---------------------------------------------------------------------------
__global__ __launch_bounds__(256, 3) void qkv_plus(
    const short* __restrict__ Axq,
    const short* __restrict__ Wq, const short* __restrict__ Wk,
    const short* __restrict__ Wv,
    const float* __restrict__ bq, const float* __restrict__ bk,
    const float* __restrict__ bv,
    short* __restrict__ oq, short* __restrict__ kall, short* __restrict__ vall,
    const float* __restrict__ mkv,
    const unsigned char* __restrict__ maskb, const int* __restrict__ mlen,
    const int* __restrict__ padv, unsigned char* __restrict__ mbits)
{
    __shared__ short As[128][64];
    __shared__ short Ws[128][64];
    const int bx = blockIdx.x;
    const int tid = threadIdx.x;

    if (bx < 768) {
        const int sel = bx >> 8;
        const int t = bx & 255;
        const int n0 = (t >> 3) * 128;
        const int j0 = (t & 7) * 128;
        if (sel == 0)
            gemm128_body<1>(As, Ws, Axq, Wq, bq, oq, n0, j0, 0.125f, nullptr);
        else if (sel == 1)
            gemm128_body<2>(As, Ws, Axq, Wk, bk, kall, n0, j0, 1.0f, mlen);
        else
            gemm128_body<3>(As, Ws, Axq, Wv, bv, vall, n0, j0, 1.0f, mlen);
        return;
    }

    if (bx < 3840) {
        // ---- mkv: [t][b][h][128] f32 -> kall[g][t][64] + vall[g][hc][t] ----
        short (*T)[72] = (short(*)[72])&As[0][0];   // 9216B alias
        const int idx = bx - 768;                 // [0, 3072)
        const int tc = idx % 24;
        const int h  = (idx / 24) & 15;
        const int b  = idx / 384;
        const int L = mlen[b];
        const int tendb = L + padv[b];
        if (tc * 64 >= tendb) return;             // chunk never read
        const int row = tid >> 2, part = tid & 3;
        const int t = tc * 64 + row;
        const int g = b * H_ + h;
        const bool skiprow = (t >= L) && (t < L + 512);   // GEMM overwrites
        short o[32];
        if (!skiprow) {
            const float4* src = (const float4*)(mkv + (((size_t)t * B_ + b) * H_ + h) * 128 + part * 32);
#pragma unroll
            for (int j = 0; j < 8; ++j) {
                float4 f = src[j];
                o[j * 4 + 0] = f2bf(f.x); o[j * 4 + 1] = f2bf(f.y);
                o[j * 4 + 2] = f2bf(f.z); o[j * 4 + 3] = f2bf(f.w);
            }
        } else {
#pragma unroll
            for (int j = 0; j < 32; ++j) o[j] = 0;
        }
        if (part < 2) {   // K half (rows disjoint from GEMM's [L,L+512))
            if (!skiprow) {
                short* d = kall + ((size_t)g * TMX + t) * 64 + part * 32;
#pragma unroll
                for (int j = 0; j < 4; ++j) ((uint4*)d)[j] = ((uint4*)o)[j];
            }
        } else {          // V half: cols 64..127 -> transpose via LDS
            int hc0 = (part - 2) * 32;
#pragma unroll
            for (int j = 0; j < 32; ++j) T[hc0 + j][row] = o[j];
        }
        __syncthreads();
        const int hc = tid >> 2, seg = tid & 3;
        const int c0 = tc * 64 + seg * 16;
        short* d = vall + ((size_t)g * HC_ + hc) * TMX + c0;
        const short* srow = &T[hc][seg * 16];
        // V-window race fix: GEMM concurrently writes vall cols [L, L+512)
        if (c0 + 16 <= L || c0 >= L + 512) {
            ((uint4*)d)[0] = *(const uint4*)&srow[0];
            ((uint4*)d)[1] = *(const uint4*)&srow[8];
        } else if (!(c0 >= L && c0 + 16 <= L + 512)) {
#pragma unroll
            for (int j = 0; j < 16; ++j) {
                int tt = c0 + j;
                if (tt < L || tt >= L + 512) d[j] = srow[j];
            }
        }
        return;
    }

    if (bx < 3968) {
        // ---- zero vall garbage window readable by the last chunk ----
        const int i = bx - 3840;                  // [0, 128)
        const int b = i >> 4, h = i & 15;
        const int L = mlen[b], P = padv[b];
        const int te = L + P;
        const int z0 = max(1536, L + 512);
        const int z1 = min(2048, (te + 63) & ~63);
        if (z1 > z0) {
            const int g = b * 16 + h;
            const int hc = tid >> 2;
            short* rowp = vall + ((size_t)g * HC_ + hc) * TMX;
            for (int c = z0 + (tid & 3); c < z1; c += 4) rowp[c] = 0;
        }
        return;
    }

    // ---- maskBits: 2048 bits per (b,q) row (256B). bit=1 -> masked. ----
    {
        const int j = bx - 3968;                  // [0, 512)
        const int b = j >> 6;
        const int q = (j & 63) * 8 + (tid >> 5);
        const int wordIdx = tid & 31;             // 64 t-values per word
        const int L = mlen[b], P = padv[b];
        const int tb = wordIdx * 64;
        unsigned long long w;
        if (tb + 63 < L) {
            w = 0ull;
        } else if (tb >= L + P) {
            w = ~0ull;
        } else {
            w = 0ull;
            const unsigned char* mq = maskb + (size_t)q * (KS_ * B_) + b;
#pragma unroll 4
            for (int k = 0; k < 64; ++k) {
                int t = tb + k;
                int bit;
                if (t < L) bit = 0;
                else {
                    int off = t - L;
                    bit = (off >= P) ? 1 : (mq[(size_t)off * B_] ? 1 : 0);
                }
                w |= (unsigned long long)bit << k;
            }
        }
        ((unsigned long long*)mbits)[(((size_t)(b * 512 + q)) << 5) + wordIdx] = w;
    }
}

__global__ __launch_bounds__(256, 3) void gemm128_f32(
    const short* __restrict__ A, const short* __restrict__ W,
    const float* __restrict__ bias, float* __restrict__ outv)
{
    __shared__ short As[128][64];
    __shared__ short Ws[128][64];
    gemm128_body<0>(As, Ws, A, W, bias, outv,
                    blockIdx.x * 128, blockIdx.y * 128, 1.0f, nullptr);
}

// ---------------------------------------------------------------------------
// Flash attention, LDS-staged 2-phase pipeline (unchanged from R7).
// ---------------------------------------------------------------------------
__global__ __launch_bounds__(256, 4) void attn_block(
    const short* __restrict__ qb, const short* __restrict__ kall,
    const short* __restrict__ vall, const unsigned char* __restrict__ mbits,
    const int* __restrict__ mlen, const int* __restrict__ padv,
    short* __restrict__ xout)
{
    __shared__ short Ks[2][64][64];   // [buf][t][hc], 128B rows, swizzled
    __shared__ short Vs[2][64][64];   // [buf][hc][t], 128B rows, swizzled

    const int tid  = threadIdx.x;
    const int lane = tid & 63;
    const int wave = tid >> 6;
    const int lr   = lane & 15;
    const int quad = lane >> 4;
    const int bx = blockIdx.x;
    const int g  = ((bx >> 6) << 3) | (bx & 7);
    const int qg = (bx >> 3) & 7;
    const int b  = g >> 4, h = g & 15;
    const int tend = mlen[b] + padv[b];
    const float NEG = -1e30f;

    const int q = qg * 64 + wave * 16 + lr;

    const short* qrow = qb + ((size_t)q * B_ + b) * C_ + h * HC_;
    bf16x8 q0 = *(const bf16x8*)(qrow + quad * 8);
    bf16x8 q1 = *(const bf16x8*)(qrow + 32 + quad * 8);

    const char* kg = (const char*)(kall + (size_t)g * TMX * 64);
    const char* vg = (const char*)(vall + (size_t)g * HC_ * TMX);
    const unsigned char* mrow = mbits + ((size_t)(b * 512 + q) << 8);  // 256B/row

    f32x4 O[4];
#pragma unroll
    for (int i = 0; i < 4; ++i) O[i] = (f32x4){0.f, 0.f, 0.f, 0.f};
    float mr = NEG, lsum = 0.f;

    const int nch = (tend + 63) >> 6;

    auto stage = [&](int t0, int buf) {
        char* KsB = (char*)Ks[buf];
        char* VsB = (char*)Vs[buf];
#pragma unroll
        for (int i = 0; i < 4; ++i) {
            int p = wave * 4 + i;
            int f = ((p & 7) << 6) + lane;        // [0,512) 16B pieces
            int row = f >> 3;
            int c = ((f & 7) << 4) ^ ((row & 7) << 4);
            if (p < 8)
                gload_lds16(kg + (size_t)(t0 + row) * 128 + c,
                            KsB + (size_t)f * 16);
            else
                gload_lds16(vg + (size_t)row * (TMX * 2) + (size_t)t0 * 2 + c,
                            VsB + (size_t)f * 16);
        }
    };

    if (nch > 0) stage(0, 0);
    __syncthreads();

    int cur = 0;
    for (int ci = 0; ci < nch; ++ci) {
        const int t0 = ci << 6;

        unsigned long long mw = *(const unsigned long long*)(mrow + (t0 >> 3));

        if (ci + 1 < nch) stage((ci + 1) << 6, cur ^ 1);

        const char* KsB = (const char*)Ks[cur];
        const char* VsB = (const char*)Vs[cur];

        bf16x8 kf[4][2];
#pragma unroll
        for (int tt = 0; tt < 4; ++tt) {
            int t = tt * 16 + lr;
            int sw = (t & 7) << 4;
            kf[tt][0] = *(const bf16x8*)(KsB + t * 128 + ((quad * 16) ^ sw));
            kf[tt][1] = *(const bf16x8*)(KsB + t * 128 + ((64 + quad * 16) ^ sw));
        }

        __builtin_amdgcn_s_setprio(1);
        f32x4 S[4];
#pragma unroll
        for (int tt = 0; tt < 4; ++tt) {
            f32x4 z = (f32x4){0.f, 0.f, 0.f, 0.f};
            z = __builtin_amdgcn_mfma_f32_16x16x32_bf16(kf[tt][0], q0, z, 0, 0, 0);
            S[tt] = __builtin_amdgcn_mfma_f32_16x16x32_bf16(kf[tt][1], q1, z, 0, 0, 0);
        }
        __builtin_amdgcn_s_setprio(0);

        bf16x8 vf[4][2];
#pragma unroll
        for (int ht = 0; ht < 4; ++ht) {
            int hc = ht * 16 + lr;
            int sw = (hc & 7) << 4;
            vf[ht][0] = *(const bf16x8*)(VsB + hc * 128 + ((quad * 16) ^ sw));
            vf[ht][1] = *(const bf16x8*)(VsB + hc * 128 + ((64 + quad * 16) ^ sw));
        }

        float p4[4][4];
#pragma unroll
        for (int tt = 0; tt < 4; ++tt) {
            unsigned m4 = ((unsigned)(mw >> (tt * 16 + quad * 4))) & 15u;
#pragma unroll
            for (int r = 0; r < 4; ++r)
                p4[tt][r] = (m4 & (1u << r)) ? NEG : S[tt][r];
        }

        float rm = NEG;
#pragma unroll
        for (int tt = 0; tt < 4; ++tt)
#pragma unroll
            for (int r = 0; r < 4; ++r) rm = fmaxf(rm, p4[tt][r]);
        rm = fmaxf(rm, __shfl_xor(rm, 16, 64));
        rm = fmaxf(rm, __shfl_xor(rm, 32, 64));
        const float nm = fmaxf(fmaxf(mr, rm), -1e20f);
        const float al = __expf(mr - nm);
        float rs = 0.f;
#pragma unroll
        for (int tt = 0; tt < 4; ++tt)
#pragma unroll
            for (int r = 0; r < 4; ++r) {
                float e = __expf(p4[tt][r] - nm);
                p4[tt][r] = e;
                rs += e;
            }
        rs += __shfl_xor(rs, 16, 64);
        rs += __shfl_xor(rs, 32, 64);
        lsum = lsum * al + rs;
        mr = nm;
#pragma unroll
        for (int ht = 0; ht < 4; ++ht)
#pragma unroll
            for (int r = 0; r < 4; ++r) O[ht][r] *= al;

        bf16x8 pf[2];
        const int slA = ((quad & 1) * 2) * 16 + lr;
        const int slB = slA + 16;
        const unsigned sel = (quad & 2) ? 0x07060302u : 0x05040100u;
#pragma unroll
        for (int hf = 0; hf < 2; ++hf) {
            const int tt0 = hf * 2;
            unsigned pk[4];
#pragma unroll
            for (int r = 0; r < 4; ++r) {
                unsigned o;
                asm("v_cvt_pk_bf16_f32 %0, %1, %2"
                    : "=v"(o) : "v"(p4[tt0][r]), "v"(p4[tt0 + 1][r]));
                pk[r] = o;
            }
            unsigned uA[4], uB[4];
#pragma unroll
            for (int r = 0; r < 4; ++r) {
                uA[r] = (unsigned)__shfl((int)pk[r], slA, 64);
                uB[r] = (unsigned)__shfl((int)pk[r], slB, 64);
            }
            unsigned wv[4];
            wv[0] = __builtin_amdgcn_perm(uA[1], uA[0], sel);
            wv[1] = __builtin_amdgcn_perm(uA[3], uA[2], sel);
            wv[2] = __builtin_amdgcn_perm(uB[1], uB[0], sel);
            wv[3] = __builtin_amdgcn_perm(uB[3], uB[2], sel);
            pf[hf] = *(const bf16x8*)wv;
        }

        __builtin_amdgcn_s_setprio(1);
#pragma unroll
        for (int ht = 0; ht < 4; ++ht) {
            O[ht] = __builtin_amdgcn_mfma_f32_16x16x32_bf16(vf[ht][0], pf[0], O[ht], 0, 0, 0);
            O[ht] = __builtin_amdgcn_mfma_f32_16x16x32_bf16(vf[ht][1], pf[1], O[ht], 0, 0, 0);
        }
        __builtin_amdgcn_s_setprio(0);

        __syncthreads();   // drains this iter's stage (vmcnt 0) + buffer reuse
        cur ^= 1;
    }

    float inv = (lsum > 0.f) ? 1.0f / lsum : 0.f;
#pragma unroll
    for (int ht = 0; ht < 4; ++ht) {
        short ov[4];
#pragma unroll
        for (int r = 0; r < 4; ++r) ov[r] = f2bf(O[ht][r] * inv);
        short* d = xout + ((size_t)q * B_ + b) * C_ + h * HC_ + ht * 16 + quad * 4;
        *(long long*)d = *(const long long*)ov;
    }
}

// ---------------------------------------------------------------------------
extern "C" void kernel_launch(void* const* d_in, const int* in_sizes, int n_in,
                              void* d_out, int out_size, void* d_ws, size_t ws_size,
                              hipStream_t stream)
{
    const float* xq   = (const float*)d_in[0];
    const int*   pad  = (const int*)d_in[1];
    const unsigned char* maskb = (const unsigned char*)d_in[2];
    const int*   mlen = (const int*)d_in[3];
    const float* mkv  = (const float*)d_in[4];
    const float* Wq   = (const float*)d_in[5];
    const float* bq   = (const float*)d_in[6];
    const float* Wk   = (const float*)d_in[7];
    const float* bk   = (const float*)d_in[8];
    const float* Wv   = (const float*)d_in[9];
    const float* bv   = (const float*)d_in[10];
    const float* Wo   = (const float*)d_in[11];
    const float* bo   = (const float*)d_in[12];
    float* out = (float*)d_out;

    // Workspace layout (shorts), ~97 MiB + 1 MiB mask bits
    short* xqb  = (short*)d_ws;
    short* wqb  = xqb  + (size_t)4194304;                 // 512*8*1024
    short* wkb  = wqb  + (size_t)1048576;
    short* wvb  = wkb  + (size_t)1048576;
    short* wob  = wvb  + (size_t)1048576;
    short* kall = wob  + (size_t)1048576;                 // 128*2048*64
    short* vall = kall + (size_t)128 * TMX * 64;          // 128*64*2048
    short* qbuf = vall + (size_t)128 * HC_ * TMX;
    short* xbuf = qbuf + (size_t)4194304;
    unsigned char* mbits = (unsigned char*)(xbuf + (size_t)4194304); // 1MB

    dim3 gblk(256);
    // 1) bf16 converts (xq + weights) — prerequisite of the QKV GEMM
    prep_cvt<<<dim3(4096), gblk, 0, stream>>>(
        xq, Wq, Wk, Wv, Wo, xqb, wqb, wkb, wvb, wob);

    // 2) fused QKV GEMM + mkv prep + V-tail zero + mask bits (one launch;
    //    prep blocks backfill the latency-bound GEMM's idle CUs)
    qkv_plus<<<dim3(4480), gblk, 0, stream>>>(
        xqb, wqb, wkb, wvb, bq, bk, bv, qbuf, kall, vall,
        mkv, maskb, mlen, pad, mbits);

    // 3) LDS-staged flash attention (all 1024 blocks co-resident)
    attn_block<<<dim3(1024), gblk, 0, stream>>>(qbuf, kall, vall, mbits,
                                                mlen, pad, xbuf);

    // 4) output projection (f32 out)
    gemm128_f32<<<dim3(32, 8), gblk, 0, stream>>>(xbuf, wob, bo, out);
}

// Round 10
// 298.064 us; speedup vs baseline: 1.9623x; 1.0185x over previous
//
#include <hip/hip_runtime.h>

// Problem constants (fixed by the reference's setup_inputs)
#define QS_ 512
#define B_  8
#define C_  1024
#define H_  16
#define HC_ 64
#define M_  1536
#define KS_ 512
#define TMX 2048   // merged K/V t-range: ceil((1535+511)/64)*64 = 2048

typedef __attribute__((ext_vector_type(8))) short bf16x8;
typedef __attribute__((ext_vector_type(4))) float f32x4;

__device__ __forceinline__ short f2bf(float f) {
    unsigned u = __float_as_uint(f);
    unsigned r = (u + 0x7FFF + ((u >> 16) & 1)) >> 16;   // RNE
    return (short)r;
}

__device__ __forceinline__ void gload_lds16(const void* g, void* l) {
    __builtin_amdgcn_global_load_lds(
        (const __attribute__((address_space(1))) unsigned int*)g,
        (__attribute__((address_space(3))) unsigned int*)l, 16, 0, 0);
}

// ---------------------------------------------------------------------------
// Converts only: f32->bf16 for xq + 4 weight matrices. 4096 blocks.
// ---------------------------------------------------------------------------
__global__ __launch_bounds__(256) void prep_cvt(
    const float* __restrict__ xq,
    const float* __restrict__ w0, const float* __restrict__ w1,
    const float* __restrict__ w2, const float* __restrict__ w3,
    short* __restrict__ xqb,
    short* __restrict__ d0, short* __restrict__ d1,
    short* __restrict__ d2, short* __restrict__ d3)
{
    int idx = blockIdx.x * 256 + threadIdx.x;     // [0, 1048576)
    const float* src; short* dst; int i;
    if (idx < 524288) { src = xq; dst = xqb; i = idx; }
    else {
        int sel = (idx >> 17) & 3;
        i = idx & 131071;
        src = sel == 0 ? w0 : sel == 1 ? w1 : sel == 2 ? w2 : w3;
        dst = sel == 0 ? d0 : sel == 1 ? d1 : sel == 2 ? d2 : d3;
    }
    const float4* s = (const float4*)src + (size_t)i * 2;
    float4 a = s[0], bq = s[1];
    short o[8];
    o[0] = f2bf(a.x);  o[1] = f2bf(a.y);  o[2] = f2bf(a.z);  o[3] = f2bf(a.w);
    o[4] = f2bf(bq.x); o[5] = f2bf(bq.y); o[6] = f2bf(bq.z); o[7] = f2bf(bq.w);
    *(uint4*)(dst + (size_t)i * 8) = *(uint4*)o;
}

// ---------------------------------------------------------------------------
// m97-style bf16 NT GEMM body: 128x128 tile, BK=64, global_load_lds width-16,
// T2 XOR-swizzled LDS. EPI: 1 = bf16 linear (oscale folds Q temperature);
// 2 = K scatter into kall; 3 = V transposed scatter into vall.
// ---------------------------------------------------------------------------
template <int EPI>
__device__ __forceinline__ void gemm128_body(
    short (*As)[64], short (*Ws)[64],
    const short* __restrict__ A, const short* __restrict__ W,
    const float* __restrict__ bias, void* __restrict__ outv,
    int n0, int j0, float oscale, const int* __restrict__ mlen)
{
    const int tid  = threadIdx.x;
    const int lane = tid & 63;
    const int wave = tid >> 6;
    const int wm = (wave & 1) * 64;
    const int wn = (wave >> 1) * 64;
    const int lr = lane & 15;
    const int quad = lane >> 4;

    f32x4 acc[4][4];
#pragma unroll
    for (int i = 0; i < 4; ++i)
#pragma unroll
        for (int j = 0; j < 4; ++j)
            acc[i][j] = (f32x4){0.f, 0.f, 0.f, 0.f};

    for (int k0 = 0; k0 < C_; k0 += 64) {
#pragma unroll
        for (int p = 0; p < 4; ++p) {
            int flat = p * 256 + tid;
            int r = flat >> 3;
            int c8 = ((flat & 7) ^ (r & 7)) * 8;   // swizzled source col (shorts)
            gload_lds16(A + (size_t)(n0 + r) * C_ + k0 + c8, (short*)As + flat * 8);
        }
#pragma unroll
        for (int p = 0; p < 4; ++p) {
            int flat = p * 256 + tid;
            int r = flat >> 3;
            int c8 = ((flat & 7) ^ (r & 7)) * 8;
            gload_lds16(W + (size_t)(j0 + r) * C_ + k0 + c8, (short*)Ws + flat * 8);
        }
        __syncthreads();
#pragma unroll
        for (int ks = 0; ks < 2; ++ks) {
            const int kkb = (ks * 32 + quad * 8) * 2;   // byte offset pre-XOR
            bf16x8 afrag[4], bfrag[4];
#pragma unroll
            for (int im = 0; im < 4; ++im) {
                int row = wm + im * 16 + lr;
                afrag[im] = *(const bf16x8*)((const char*)As + row * 128 + (kkb ^ ((row & 7) << 4)));
            }
#pragma unroll
            for (int jn = 0; jn < 4; ++jn) {
                int row = wn + jn * 16 + lr;
                bfrag[jn] = *(const bf16x8*)((const char*)Ws + row * 128 + (kkb ^ ((row & 7) << 4)));
            }
#pragma unroll
            for (int im = 0; im < 4; ++im)
#pragma unroll
                for (int jn = 0; jn < 4; ++jn)
                    acc[im][jn] = __builtin_amdgcn_mfma_f32_16x16x32_bf16(
                        afrag[im], bfrag[jn], acc[im][jn], 0, 0, 0);
        }
        __syncthreads();
    }

    if constexpr (EPI == 2 || EPI == 3) {
        int ml[8];
#pragma unroll
        for (int i = 0; i < 8; ++i) ml[i] = mlen[i];
#pragma unroll
        for (int jn = 0; jn < 4; ++jn) {
            const int col = j0 + wn + jn * 16 + lr;
            const int h = col >> 6, hc = col & 63;
            const float bv = bias[col];
#pragma unroll
            for (int im = 0; im < 4; ++im) {
                const int row = n0 + wm + im * 16 + quad * 4;
#pragma unroll
                for (int r = 0; r < 4; ++r) {
                    const int rr = row + r;
                    const int s = rr >> 3, b = rr & 7;
                    float v = acc[im][jn][r] + bv;
                    if (EPI == 2)        // K: row t = L+s, dense hc
                        ((short*)outv)[((size_t)((b * 16 + h) * TMX) + ml[b] + s) * 64 + hc] = f2bf(v);
                    else                 // V: row hc, col t = L+s
                        ((short*)outv)[((size_t)((b * 16 + h) * 64 + hc)) * TMX + ml[b] + s] = f2bf(v);
                }
            }
        }
    } else {
#pragma unroll
        for (int jn = 0; jn < 4; ++jn) {
            const int col = j0 + wn + jn * 16 + lr;
            const float bv = bias[col];
#pragma unroll
            for (int im = 0; im < 4; ++im) {
                const int row = n0 + wm + im * 16 + quad * 4;
#pragma unroll
                for (int r = 0; r < 4; ++r) {
                    float v = (acc[im][jn][r] + bv) * oscale;
                    ((short*)outv)[(size_t)(row + r) * C_ + col] = f2bf(v);
                }
            }
        }
    }
}

// ---------------------------------------------------------------------------
// Fused QKV projection + memory-KV prep + V-tail zero + mask-bit build.
//  [0,768)      : QKV GEMM (Q->qbuf x0.125, K->kall, V->vall scatter)
//  [768,3840)   : memory_kv -> kall/vall (skips dead + GEMM-overwritten)
//  [3840,3968)  : zero vall tail window
//  [3968,4480)  : maskBits
// ---------------------------------------------------------------------------
__global__ __launch_bounds__(256, 3) void qkv_plus(
    const short* __restrict__ Axq,
    const short* __restrict__ Wq, const short* __restrict__ Wk,
    const short* __restrict__ Wv,
    const float* __restrict__ bq, const float* __restrict__ bk,
    const float* __restrict__ bv,
    short* __restrict__ oq, short* __restrict__ kall, short* __restrict__ vall,
    const float* __restrict__ mkv,
    const unsigned char* __restrict__ maskb, const int* __restrict__ mlen,
    const int* __restrict__ padv, unsigned char* __restrict__ mbits)
{
    __shared__ short As[128][64];
    __shared__ short Ws[128][64];
    const int bx = blockIdx.x;
    const int tid = threadIdx.x;

    if (bx < 768) {
        const int sel = bx >> 8;
        const int t = bx & 255;
        const int n0 = (t >> 3) * 128;
        const int j0 = (t & 7) * 128;
        if (sel == 0)
            gemm128_body<1>(As, Ws, Axq, Wq, bq, oq, n0, j0, 0.125f, nullptr);
        else if (sel == 1)
            gemm128_body<2>(As, Ws, Axq, Wk, bk, kall, n0, j0, 1.0f, mlen);
        else
            gemm128_body<3>(As, Ws, Axq, Wv, bv, vall, n0, j0, 1.0f, mlen);
        return;
    }

    if (bx < 3840) {
        // ---- mkv: [t][b][h][128] f32 -> kall[g][t][64] + vall[g][hc][t] ----
        short (*T)[72] = (short(*)[72])&As[0][0];   // 9216B alias
        const int idx = bx - 768;                 // [0, 3072)
        const int tc = idx % 24;
        const int h  = (idx / 24) & 15;
        const int b  = idx / 384;
        const int L = mlen[b];
        const int tendb = L + padv[b];
        if (tc * 64 >= tendb) return;             // chunk never read
        const int row = tid >> 2, part = tid & 3;
        const int t = tc * 64 + row;
        const int g = b * H_ + h;
        const bool skiprow = (t >= L) && (t < L + 512);   // GEMM overwrites
        short o[32];
        if (!skiprow) {
            const float4* src = (const float4*)(mkv + (((size_t)t * B_ + b) * H_ + h) * 128 + part * 32);
#pragma unroll
            for (int j = 0; j < 8; ++j) {
                float4 f = src[j];
                o[j * 4 + 0] = f2bf(f.x); o[j * 4 + 1] = f2bf(f.y);
                o[j * 4 + 2] = f2bf(f.z); o[j * 4 + 3] = f2bf(f.w);
            }
        } else {
#pragma unroll
            for (int j = 0; j < 32; ++j) o[j] = 0;
        }
        if (part < 2) {   // K half (rows disjoint from GEMM's [L,L+512))
            if (!skiprow) {
                short* d = kall + ((size_t)g * TMX + t) * 64 + part * 32;
#pragma unroll
                for (int j = 0; j < 4; ++j) ((uint4*)d)[j] = ((uint4*)o)[j];
            }
        } else {          // V half: cols 64..127 -> transpose via LDS
            int hc0 = (part - 2) * 32;
#pragma unroll
            for (int j = 0; j < 32; ++j) T[hc0 + j][row] = o[j];
        }
        __syncthreads();
        const int hc = tid >> 2, seg = tid & 3;
        const int c0 = tc * 64 + seg * 16;
        short* d = vall + ((size_t)g * HC_ + hc) * TMX + c0;
        const short* srow = &T[hc][seg * 16];
        // V-window race fix: GEMM concurrently writes vall cols [L, L+512)
        if (c0 + 16 <= L || c0 >= L + 512) {
            ((uint4*)d)[0] = *(const uint4*)&srow[0];
            ((uint4*)d)[1] = *(const uint4*)&srow[8];
        } else if (!(c0 >= L && c0 + 16 <= L + 512)) {
#pragma unroll
            for (int j = 0; j < 16; ++j) {
                int tt = c0 + j;
                if (tt < L || tt >= L + 512) d[j] = srow[j];
            }
        }
        return;
    }

    if (bx < 3968) {
        // ---- zero vall garbage window readable by the last chunk ----
        const int i = bx - 3840;                  // [0, 128)
        const int b = i >> 4, h = i & 15;
        const int L = mlen[b], P = padv[b];
        const int te = L + P;
        const int z0 = max(1536, L + 512);
        const int z1 = min(2048, (te + 63) & ~63);
        if (z1 > z0) {
            const int g = b * 16 + h;
            const int hc = tid >> 2;
            short* rowp = vall + ((size_t)g * HC_ + hc) * TMX;
            for (int c = z0 + (tid & 3); c < z1; c += 4) rowp[c] = 0;
        }
        return;
    }

    // ---- maskBits: 2048 bits per (b,q) row (256B). bit=1 -> masked. ----
    {
        const int j = bx - 3968;                  // [0, 512)
        const int b = j >> 6;
        const int q = (j & 63) * 8 + (tid >> 5);
        const int wordIdx = tid & 31;             // 64 t-values per word
        const int L = mlen[b], P = padv[b];
        const int tb = wordIdx * 64;
        unsigned long long w;
        if (tb + 63 < L) {
            w = 0ull;
        } else if (tb >= L + P) {
            w = ~0ull;
        } else {
            w = 0ull;
            const unsigned char* mq = maskb + (size_t)q * (KS_ * B_) + b;
#pragma unroll 4
            for (int k = 0; k < 64; ++k) {
                int t = tb + k;
                int bit;
                if (t < L) bit = 0;
                else {
                    int off = t - L;
                    bit = (off >= P) ? 1 : (mq[(size_t)off * B_] ? 1 : 0);
                }
                w |= (unsigned long long)bit << k;
            }
        }
        ((unsigned long long*)mbits)[(((size_t)(b * 512 + q)) << 5) + wordIdx] = w;
    }
}

// ---------------------------------------------------------------------------
// Output projection, 64x64 tiles: grid (64,16) = 1024 blocks = 4 blocks/CU
// (the old 128x128 grid (32,8) was 1 block/CU -> latency-exposed like the
// pre-fusion QKV). Same total MFMA; 16KB LDS; 4 waves each 32x32.
// ---------------------------------------------------------------------------
__global__ __launch_bounds__(256) void gemm64_f32(
    const short* __restrict__ A, const short* __restrict__ W,
    const float* __restrict__ bias, float* __restrict__ outv)
{
    __shared__ short As[64][64];
    __shared__ short Ws[64][64];
    const int tid  = threadIdx.x;
    const int lane = tid & 63;
    const int wave = tid >> 6;
    const int wm = (wave & 1) * 32;
    const int wn = (wave >> 1) * 32;
    const int lr = lane & 15;
    const int quad = lane >> 4;
    const int n0 = blockIdx.x * 64;
    const int j0 = blockIdx.y * 64;

    f32x4 acc[2][2];
#pragma unroll
    for (int i = 0; i < 2; ++i)
#pragma unroll
        for (int j = 0; j < 2; ++j)
            acc[i][j] = (f32x4){0.f, 0.f, 0.f, 0.f};

    for (int k0 = 0; k0 < C_; k0 += 64) {
#pragma unroll
        for (int p = 0; p < 2; ++p) {
            int flat = p * 256 + tid;              // [0,512) 16B pieces
            int r = flat >> 3;
            int c8 = ((flat & 7) ^ (r & 7)) * 8;
            gload_lds16(A + (size_t)(n0 + r) * C_ + k0 + c8, (short*)As + flat * 8);
        }
#pragma unroll
        for (int p = 0; p < 2; ++p) {
            int flat = p * 256 + tid;
            int r = flat >> 3;
            int c8 = ((flat & 7) ^ (r & 7)) * 8;
            gload_lds16(W + (size_t)(j0 + r) * C_ + k0 + c8, (short*)Ws + flat * 8);
        }
        __syncthreads();
#pragma unroll
        for (int ks = 0; ks < 2; ++ks) {
            const int kkb = (ks * 32 + quad * 8) * 2;
            bf16x8 afrag[2], bfrag[2];
#pragma unroll
            for (int im = 0; im < 2; ++im) {
                int row = wm + im * 16 + lr;
                afrag[im] = *(const bf16x8*)((const char*)As + row * 128 + (kkb ^ ((row & 7) << 4)));
            }
#pragma unroll
            for (int jn = 0; jn < 2; ++jn) {
                int row = wn + jn * 16 + lr;
                bfrag[jn] = *(const bf16x8*)((const char*)Ws + row * 128 + (kkb ^ ((row & 7) << 4)));
            }
#pragma unroll
            for (int im = 0; im < 2; ++im)
#pragma unroll
                for (int jn = 0; jn < 2; ++jn)
                    acc[im][jn] = __builtin_amdgcn_mfma_f32_16x16x32_bf16(
                        afrag[im], bfrag[jn], acc[im][jn], 0, 0, 0);
        }
        __syncthreads();
    }

#pragma unroll
    for (int jn = 0; jn < 2; ++jn) {
        const int col = j0 + wn + jn * 16 + lr;
        const float bv = bias[col];
#pragma unroll
        for (int im = 0; im < 2; ++im) {
            const int row = n0 + wm + im * 16 + quad * 4;
#pragma unroll
            for (int r = 0; r < 4; ++r)
                outv[(size_t)(row + r) * C_ + col] = acc[im][jn][r] + bv;
        }
    }
}

// ---------------------------------------------------------------------------
// Flash attention, LDS-staged 2-phase pipeline. Cross-lane ops are the
// R8-proven shfl/cvt_pk/v_perm path (R9's permlane-swap rewrite reverted:
// the swap's operand-direction is undocumented and the P^T gather is
// direction-sensitive -- it produced absmax 0.19).
// ---------------------------------------------------------------------------
__global__ __launch_bounds__(256, 4) void attn_block(
    const short* __restrict__ qb, const short* __restrict__ kall,
    const short* __restrict__ vall, const unsigned char* __restrict__ mbits,
    const int* __restrict__ mlen, const int* __restrict__ padv,
    short* __restrict__ xout)
{
    __shared__ short Ks[2][64][64];   // [buf][t][hc], 128B rows, swizzled
    __shared__ short Vs[2][64][64];   // [buf][hc][t], 128B rows, swizzled

    const int tid  = threadIdx.x;
    const int lane = tid & 63;
    const int wave = tid >> 6;
    const int lr   = lane & 15;
    const int quad = lane >> 4;
    const int bx = blockIdx.x;
    const int g  = ((bx >> 6) << 3) | (bx & 7);
    const int qg = (bx >> 3) & 7;
    const int b  = g >> 4, h = g & 15;
    const int tend = mlen[b] + padv[b];
    const float NEG = -1e30f;

    const int q = qg * 64 + wave * 16 + lr;

    const short* qrow = qb + ((size_t)q * B_ + b) * C_ + h * HC_;
    bf16x8 q0 = *(const bf16x8*)(qrow + quad * 8);
    bf16x8 q1 = *(const bf16x8*)(qrow + 32 + quad * 8);

    const char* kg = (const char*)(kall + (size_t)g * TMX * 64);
    const char* vg = (const char*)(vall + (size_t)g * HC_ * TMX);
    const unsigned char* mrow = mbits + ((size_t)(b * 512 + q) << 8);  // 256B/row

    f32x4 O[4];
#pragma unroll
    for (int i = 0; i < 4; ++i) O[i] = (f32x4){0.f, 0.f, 0.f, 0.f};
    float mr = NEG, lsum = 0.f;

    const int nch = (tend + 63) >> 6;

    auto stage = [&](int t0, int buf) {
        char* KsB = (char*)Ks[buf];
        char* VsB = (char*)Vs[buf];
#pragma unroll
        for (int i = 0; i < 4; ++i) {
            int p = wave * 4 + i;
            int f = ((p & 7) << 6) + lane;        // [0,512) 16B pieces
            int row = f >> 3;
            int c = ((f & 7) << 4) ^ ((row & 7) << 4);
            if (p < 8)
                gload_lds16(kg + (size_t)(t0 + row) * 128 + c,
                            KsB + (size_t)f * 16);
            else
                gload_lds16(vg + (size_t)row * (TMX * 2) + (size_t)t0 * 2 + c,
                            VsB + (size_t)f * 16);
        }
    };

    if (nch > 0) stage(0, 0);
    __syncthreads();

    int cur = 0;
    for (int ci = 0; ci < nch; ++ci) {
        const int t0 = ci << 6;

        unsigned long long mw = *(const unsigned long long*)(mrow + (t0 >> 3));

        if (ci + 1 < nch) stage((ci + 1) << 6, cur ^ 1);

        const char* KsB = (const char*)Ks[cur];
        const char* VsB = (const char*)Vs[cur];

        bf16x8 kf[4][2];
#pragma unroll
        for (int tt = 0; tt < 4; ++tt) {
            int t = tt * 16 + lr;
            int sw = (t & 7) << 4;
            kf[tt][0] = *(const bf16x8*)(KsB + t * 128 + ((quad * 16) ^ sw));
            kf[tt][1] = *(const bf16x8*)(KsB + t * 128 + ((64 + quad * 16) ^ sw));
        }

        __builtin_amdgcn_s_setprio(1);
        f32x4 S[4];
#pragma unroll
        for (int tt = 0; tt < 4; ++tt) {
            f32x4 z = (f32x4){0.f, 0.f, 0.f, 0.f};
            z = __builtin_amdgcn_mfma_f32_16x16x32_bf16(kf[tt][0], q0, z, 0, 0, 0);
            S[tt] = __builtin_amdgcn_mfma_f32_16x16x32_bf16(kf[tt][1], q1, z, 0, 0, 0);
        }
        __builtin_amdgcn_s_setprio(0);

        bf16x8 vf[4][2];
#pragma unroll
        for (int ht = 0; ht < 4; ++ht) {
            int hc = ht * 16 + lr;
            int sw = (hc & 7) << 4;
            vf[ht][0] = *(const bf16x8*)(VsB + hc * 128 + ((quad * 16) ^ sw));
            vf[ht][1] = *(const bf16x8*)(VsB + hc * 128 + ((64 + quad * 16) ^ sw));
        }

        float p4[4][4];
#pragma unroll
        for (int tt = 0; tt < 4; ++tt) {
            unsigned m4 = ((unsigned)(mw >> (tt * 16 + quad * 4))) & 15u;
#pragma unroll
            for (int r = 0; r < 4; ++r)
                p4[tt][r] = (m4 & (1u << r)) ? NEG : S[tt][r];
        }

        // ---- online softmax (cross-quad reduce via xor 16,32) ----
        float rm = NEG;
#pragma unroll
        for (int tt = 0; tt < 4; ++tt)
#pragma unroll
            for (int r = 0; r < 4; ++r) rm = fmaxf(rm, p4[tt][r]);
        rm = fmaxf(rm, __shfl_xor(rm, 16, 64));
        rm = fmaxf(rm, __shfl_xor(rm, 32, 64));
        const float nm = fmaxf(fmaxf(mr, rm), -1e20f);
        const float al = __expf(mr - nm);
        float rs = 0.f;
#pragma unroll
        for (int tt = 0; tt < 4; ++tt)
#pragma unroll
            for (int r = 0; r < 4; ++r) {
                float e = __expf(p4[tt][r] - nm);
                p4[tt][r] = e;
                rs += e;
            }
        rs += __shfl_xor(rs, 16, 64);
        rs += __shfl_xor(rs, 32, 64);
        lsum = lsum * al + rs;
        mr = nm;
#pragma unroll
        for (int ht = 0; ht < 4; ++ht)
#pragma unroll
            for (int r = 0; r < 4; ++r) O[ht][r] *= al;

        // ---- P^T fragments: pack to bf16 before shuffling ----
        bf16x8 pf[2];
        const int slA = ((quad & 1) * 2) * 16 + lr;
        const int slB = slA + 16;
        const unsigned sel = (quad & 2) ? 0x07060302u : 0x05040100u;
#pragma unroll
        for (int hf = 0; hf < 2; ++hf) {
            const int tt0 = hf * 2;
            unsigned pk[4];
#pragma unroll
            for (int r = 0; r < 4; ++r) {
                unsigned o;
                asm("v_cvt_pk_bf16_f32 %0, %1, %2"
                    : "=v"(o) : "v"(p4[tt0][r]), "v"(p4[tt0 + 1][r]));
                pk[r] = o;
            }
            unsigned uA[4], uB[4];
#pragma unroll
            for (int r = 0; r < 4; ++r) {
                uA[r] = (unsigned)__shfl((int)pk[r], slA, 64);
                uB[r] = (unsigned)__shfl((int)pk[r], slB, 64);
            }
            unsigned wv[4];
            wv[0] = __builtin_amdgcn_perm(uA[1], uA[0], sel);
            wv[1] = __builtin_amdgcn_perm(uA[3], uA[2], sel);
            wv[2] = __builtin_amdgcn_perm(uB[1], uB[0], sel);
            wv[3] = __builtin_amdgcn_perm(uB[3], uB[2], sel);
            pf[hf] = *(const bf16x8*)wv;
        }

        __builtin_amdgcn_s_setprio(1);
#pragma unroll
        for (int ht = 0; ht < 4; ++ht) {
            O[ht] = __builtin_amdgcn_mfma_f32_16x16x32_bf16(vf[ht][0], pf[0], O[ht], 0, 0, 0);
            O[ht] = __builtin_amdgcn_mfma_f32_16x16x32_bf16(vf[ht][1], pf[1], O[ht], 0, 0, 0);
        }
        __builtin_amdgcn_s_setprio(0);

        __syncthreads();   // drains this iter's stage (vmcnt 0) + buffer reuse
        cur ^= 1;
    }

    float inv = (lsum > 0.f) ? 1.0f / lsum : 0.f;
#pragma unroll
    for (int ht = 0; ht < 4; ++ht) {
        short ov[4];
#pragma unroll
        for (int r = 0; r < 4; ++r) ov[r] = f2bf(O[ht][r] * inv);
        short* d = xout + ((size_t)q * B_ + b) * C_ + h * HC_ + ht * 16 + quad * 4;
        *(long long*)d = *(const long long*)ov;
    }
}

// ---------------------------------------------------------------------------
extern "C" void kernel_launch(void* const* d_in, const int* in_sizes, int n_in,
                              void* d_out, int out_size, void* d_ws, size_t ws_size,
                              hipStream_t stream)
{
    const float* xq   = (const float*)d_in[0];
    const int*   pad  = (const int*)d_in[1];
    const unsigned char* maskb = (const unsigned char*)d_in[2];
    const int*   mlen = (const int*)d_in[3];
    const float* mkv  = (const float*)d_in[4];
    const float* Wq   = (const float*)d_in[5];
    const float* bq   = (const float*)d_in[6];
    const float* Wk   = (const float*)d_in[7];
    const float* bk   = (const float*)d_in[8];
    const float* Wv   = (const float*)d_in[9];
    const float* bv   = (const float*)d_in[10];
    const float* Wo   = (const float*)d_in[11];
    const float* bo   = (const float*)d_in[12];
    float* out = (float*)d_out;

    // Workspace layout (shorts), ~97 MiB + 1 MiB mask bits
    short* xqb  = (short*)d_ws;
    short* wqb  = xqb  + (size_t)4194304;                 // 512*8*1024
    short* wkb  = wqb  + (size_t)1048576;
    short* wvb  = wkb  + (size_t)1048576;
    short* wob  = wvb  + (size_t)1048576;
    short* kall = wob  + (size_t)1048576;                 // 128*2048*64
    short* vall = kall + (size_t)128 * TMX * 64;          // 128*64*2048
    short* qbuf = vall + (size_t)128 * HC_ * TMX;
    short* xbuf = qbuf + (size_t)4194304;
    unsigned char* mbits = (unsigned char*)(xbuf + (size_t)4194304); // 1MB

    dim3 gblk(256);
    // 1) bf16 converts (xq + weights) — prerequisite of the QKV GEMM
    prep_cvt<<<dim3(4096), gblk, 0, stream>>>(
        xq, Wq, Wk, Wv, Wo, xqb, wqb, wkb, wvb, wob);

    // 2) fused QKV GEMM + mkv prep + V-tail zero + mask bits
    qkv_plus<<<dim3(4480), gblk, 0, stream>>>(
        xqb, wqb, wkb, wvb, bq, bk, bv, qbuf, kall, vall,
        mkv, maskb, mlen, pad, mbits);

    // 3) LDS-staged flash attention (all 1024 blocks co-resident)
    attn_block<<<dim3(1024), gblk, 0, stream>>>(qbuf, kall, vall, mbits,
                                                mlen, pad, xbuf);

    // 4) output projection (f32 out), 64x64 tiles, 4 blocks/CU
    gemm64_f32<<<dim3(64, 16), gblk, 0, stream>>>(xbuf, wob, bo, out);
}